// Round 13
// baseline (631.699 us; speedup 1.0000x reference)
//
#include <hip/hip_runtime.h>
#include <hip/hip_bf16.h>
#include <stdint.h>

#define N_NODES 6144
#define N_DRUG  3072
#define N_EDGE  196608
#define E_TOT   (N_EDGE + N_NODES)
#define GAMMA   0.03125f
#define LOG2E   1.44269504f

typedef __bf16 bf16x8 __attribute__((ext_vector_type(8)));
typedef float  f32x4  __attribute__((ext_vector_type(4)));

__device__ __forceinline__ unsigned short f2b(float f){
  union { float f; unsigned u; } v; v.f = f;
  unsigned r = v.u + 0x7FFFu + ((v.u >> 16) & 1u);
  return (unsigned short)(r >> 16);
}
__device__ __forceinline__ float b2f(unsigned short b){
  union { unsigned u; float f; } v; v.u = ((unsigned)b) << 16;
  return v.f;
}
__device__ __forceinline__ float fexp2(float x){
  float r; asm("v_exp_f32 %0, %1" : "=v"(r) : "v"(x)); return r;
}
__device__ __forceinline__ void gl_lds(const void* g, void* l){
  __builtin_amdgcn_global_load_lds((const __attribute__((address_space(1))) void*)g,
                                   (__attribute__((address_space(3))) void*)l, 16, 0, 0);
}

#define WAITVM(N) asm volatile("s_waitcnt vmcnt(" #N ")" ::: "memory")
#define SYNC() { __builtin_amdgcn_sched_barrier(0); __builtin_amdgcn_s_barrier(); __builtin_amdgcn_sched_barrier(0); }

// ---------------- elementwise / transpose casts ----------------
__global__ void cast_bf16_k(const float* __restrict__ in, unsigned short* __restrict__ out, long n){
  long i = ((long)blockIdx.x*blockDim.x + threadIdx.x)*4;
  long stride = (long)gridDim.x*blockDim.x*4;
  for (; i < n; i += stride){
    float4 v = *(const float4*)(in + i);
    ushort4 o;
    o.x = f2b(v.x); o.y = f2b(v.y); o.z = f2b(v.z); o.w = f2b(v.w);
    *(ushort4*)(out + i) = o;
  }
}

// out[c][OLD] at [c][OOFF + r] = bf16(in[r][c]); in is [R][Cd]
__global__ void tcast_k(const float* __restrict__ in, unsigned short* __restrict__ out,
                        int R, int Cd, int OLD, int OOFF){
  __shared__ float tile[32][33];
  int bx = blockIdx.x*32, by = blockIdx.y*32;
  int tx = threadIdx.x, ty = threadIdx.y;
  for (int i = ty; i < 32; i += 8) tile[i][tx] = in[(long)(by+i)*Cd + bx + tx];
  __syncthreads();
  for (int i = ty; i < 32; i += 8) out[(long)(bx+i)*OLD + OOFF + by + tx] = f2b(tile[tx][i]);
}

// z=0: alpha2 -> o0 at OOFF=N_DRUG ; z=1: alpha1 -> o1 at OOFF=0  (both 3072^2, OLD=N_NODES)
__global__ void tcast2_k(const float* __restrict__ a2, const float* __restrict__ a1,
                         unsigned short* __restrict__ o0, unsigned short* __restrict__ o1){
  __shared__ float tile[32][33];
  const float* in = blockIdx.z ? a1 : a2;
  unsigned short* out = blockIdx.z ? o1 : o0;
  int OOFF = blockIdx.z ? 0 : N_DRUG;
  int bx = blockIdx.x*32, by = blockIdx.y*32;
  int tx = threadIdx.x, ty = threadIdx.y;
  for (int i = ty; i < 32; i += 8) tile[i][tx] = in[(long)(by+i)*N_DRUG + bx + tx];
  __syncthreads();
  for (int i = ty; i < 32; i += 8) out[(long)(bx+i)*N_NODES + OOFF + by + tx] = f2b(tile[tx][i]);
}

// ---------------- CSR build ----------------
__global__ void hist_k(const int* __restrict__ ei, int* __restrict__ cnt){
  int i = blockIdx.x*blockDim.x + threadIdx.x;
  if (i >= E_TOT) return;
  int d = (i < N_EDGE) ? ei[N_EDGE + i] : (i - N_EDGE);
  atomicAdd(&cnt[d], 1);
}

__global__ void scan_k(const int* __restrict__ cnt, int* __restrict__ ptr){
  __shared__ int sums[1024];
  int t = threadIdx.x;
  int v[6]; int s = 0;
  #pragma unroll
  for (int i = 0; i < 6; i++){ v[i] = s; s += cnt[t*6 + i]; }
  sums[t] = s; __syncthreads();
  for (int off = 1; off < 1024; off <<= 1){
    int add = (t >= off) ? sums[t - off] : 0;
    __syncthreads();
    sums[t] += add;
    __syncthreads();
  }
  int base = (t == 0) ? 0 : sums[t-1];
  #pragma unroll
  for (int i = 0; i < 6; i++) ptr[t*6 + i] = base + v[i];
  if (t == 1023) ptr[N_NODES] = sums[1023];
}

// one-time: CSR scatter + adj gather into CSR order (layer-invariant edge weights)
__global__ void scatter_k(const int* __restrict__ ei, const float* __restrict__ adj,
                          const int* __restrict__ ptr, int* __restrict__ cur,
                          int* __restrict__ srcs, int* __restrict__ dsts,
                          float* __restrict__ wcsr){
  int i = blockIdx.x*blockDim.x + threadIdx.x;
  if (i >= E_TOT) return;
  int s = (i < N_EDGE) ? ei[i] : (i - N_EDGE);
  int d = (i < N_EDGE) ? ei[N_EDGE + i] : (i - N_EDGE);
  int pos = ptr[d] + atomicAdd(&cur[d], 1);
  srcs[pos] = s; dsts[pos] = d;
  wcsr[pos] = (i < N_EDGE) ? adj[(long)s*N_NODES + d] : 1.0f;
}

// ---------------- GAT pieces ----------------
// reads bf16 XWb via ushort4; also zeroes denom for phase12
__global__ void dots_k(const unsigned short* __restrict__ XWb, const float* __restrict__ av,
                       const float* __restrict__ dv, float* __restrict__ es,
                       float* __restrict__ ed, float* __restrict__ denom, int F){
  int n = blockIdx.x, l = threadIdx.x;
  float s = 0.f, d = 0.f;
  for (int f = l*4; f < F; f += 256){
    ushort4 u = *(const ushort4*)(XWb + (long)n*F + f);
    float4 a = *(const float4*)(av + f);
    float4 dd = *(const float4*)(dv + f);
    s += b2f(u.x)*a.x + b2f(u.y)*a.y + b2f(u.z)*a.z + b2f(u.w)*a.w;
    d += b2f(u.x)*dd.x + b2f(u.y)*dd.y + b2f(u.z)*dd.z + b2f(u.w)*dd.w;
  }
  #pragma unroll
  for (int off = 32; off > 0; off >>= 1){ s += __shfl_down(s, off); d += __shfl_down(d, off); }
  if (l == 0){ es[n] = s; ed[n] = d; denom[n] = 0.f; }
}

// iterate by CSR position: all streams coalesced; es/ed gathers are L2-resident
__global__ void phase12_k(const int* __restrict__ srcs, const int* __restrict__ dsts,
                          const float* __restrict__ wcsr,
                          const float* __restrict__ es, const float* __restrict__ ed,
                          float* __restrict__ exc, float* __restrict__ denom){
  int p = blockIdx.x*blockDim.x + threadIdx.x;
  if (p >= E_TOT) return;
  int s = srcs[p], d = dsts[p];
  float e = es[s] + ed[d];
  e = (e > 0.f) ? e : 0.2f*e;
  float ex = fexp2(e * LOG2E) * wcsr[p];
  exc[p] = ex;
  atomicAdd(&denom[d], ex);
}

// one block per node; blockDim = F/4; ushort4 (4 bf16) gathers (F >= 256); bf16 out only
__global__ void agg4_k(const unsigned short* __restrict__ XWb, const int* __restrict__ ptr,
                       const int* __restrict__ srcs, const float* __restrict__ exc,
                       const float* __restrict__ denom, const float* __restrict__ bias,
                       unsigned short* __restrict__ Hb, int F){
  int n = blockIdx.x, t = threadIdx.x;
  int st = ptr[n], en = ptr[n+1];
  float a0v = 0.f, a1v = 0.f, a2v = 0.f, a3v = 0.f;
  int j = st;
  for (; j + 1 < en; j += 2){
    float w0 = exc[j], w1 = exc[j+1];
    int s0 = srcs[j], s1 = srcs[j+1];
    ushort4 u0 = *(const ushort4*)(XWb + (long)s0*F + t*4);
    ushort4 u1 = *(const ushort4*)(XWb + (long)s1*F + t*4);
    a0v += w0*b2f(u0.x) + w1*b2f(u1.x); a1v += w0*b2f(u0.y) + w1*b2f(u1.y);
    a2v += w0*b2f(u0.z) + w1*b2f(u1.z); a3v += w0*b2f(u0.w) + w1*b2f(u1.w);
  }
  if (j < en){
    float w0 = exc[j]; int s0 = srcs[j];
    ushort4 u0 = *(const ushort4*)(XWb + (long)s0*F + t*4);
    a0v += w0*b2f(u0.x); a1v += w0*b2f(u0.y); a2v += w0*b2f(u0.z); a3v += w0*b2f(u0.w);
  }
  float invd = 1.f/(denom[n] + 1e-16f);
  float4 b = *(const float4*)(bias + t*4);
  ushort4 ob;
  ob.x = f2b(fmaxf(a0v*invd + b.x, 0.f)); ob.y = f2b(fmaxf(a1v*invd + b.y, 0.f));
  ob.z = f2b(fmaxf(a2v*invd + b.z, 0.f)); ob.w = f2b(fmaxf(a3v*invd + b.w, 0.f));
  *(ushort4*)(Hb + (long)n*F + t*4) = ob;
}

// F = 128 variant: blockDim = 64, ushort2 per thread
__global__ void agg_k(const unsigned short* __restrict__ XWb, const int* __restrict__ ptr,
                      const int* __restrict__ srcs, const float* __restrict__ exc,
                      const float* __restrict__ denom, const float* __restrict__ bias,
                      unsigned short* __restrict__ Hb, int F){
  int n = blockIdx.x, t = threadIdx.x;
  int st = ptr[n], en = ptr[n+1];
  float ax = 0.f, ay = 0.f;
  int j = st;
  for (; j + 1 < en; j += 2){
    float a0 = exc[j], a1 = exc[j+1];
    int s0 = srcs[j], s1 = srcs[j+1];
    ushort2 u0 = *(const ushort2*)(XWb + (long)s0*F + t*2);
    ushort2 u1 = *(const ushort2*)(XWb + (long)s1*F + t*2);
    ax += a0*b2f(u0.x) + a1*b2f(u1.x);
    ay += a0*b2f(u0.y) + a1*b2f(u1.y);
  }
  if (j < en){
    float a = exc[j]; int s = srcs[j];
    ushort2 u = *(const ushort2*)(XWb + (long)s*F + t*2);
    ax += a*b2f(u.x); ay += a*b2f(u.y);
  }
  float invd = 1.f/(denom[n] + 1e-16f);
  float2 b = *(const float2*)(bias + t*2);
  ushort2 o;
  o.x = f2b(fmaxf(ax*invd + b.x, 0.f));
  o.y = f2b(fmaxf(ay*invd + b.y, 0.f));
  *(ushort2*)(Hb + (long)n*F + t*2) = o;
}

// ---------------- GIP prep (merged over 6 segments: seg = side*3 + layer) ------
__global__ void rownorm_all_k(const unsigned short* __restrict__ H0, const unsigned short* __restrict__ H1,
                              const unsigned short* __restrict__ H2,
                              unsigned short* __restrict__ y0, unsigned short* __restrict__ y1,
                              float* __restrict__ dv0, float* __restrict__ dv1){
  int seg = blockIdx.y;
  int side = seg / 3, layer = seg % 3;
  int F = 512 >> layer;
  const unsigned short* H = (layer == 0) ? H0 : (layer == 1) ? H1 : H2;
  H += (size_t)(side ? N_DRUG : 0) * F;
  unsigned short* yb = ((side ? y1 : y0) + ((layer == 0) ? 0 : (layer == 1) ? 512 : 768));
  float* dvec = (side ? dv1 : dv0) + layer*N_DRUG;

  int r = blockIdx.x, t = threadIdx.x;
  __shared__ float ra[256], rb[256];
  float mn = 3.4e38f, mx = -3.4e38f;
  for (int f = t; f < F; f += 256){
    float v = b2f(H[(long)r*F + f]);
    mn = fminf(mn, v); mx = fmaxf(mx, v);
  }
  ra[t] = mn; rb[t] = mx; __syncthreads();
  for (int s2 = 128; s2 > 0; s2 >>= 1){
    if (t < s2){ ra[t] = fminf(ra[t], ra[t+s2]); rb[t] = fmaxf(rb[t], rb[t+s2]); }
    __syncthreads();
  }
  mn = ra[0]; mx = rb[0];
  __syncthreads();
  float sc = 1.f/(mx - mn + 1e-12f);
  float s = 0.f;
  for (int f = t; f < F; f += 256){
    float v = (b2f(H[(long)r*F + f]) - mn)*sc;
    unsigned short b = f2b(v);
    yb[(long)r*896 + f] = b;
    float vb = b2f(b);
    s += vb*vb;
  }
  ra[t] = s; __syncthreads();
  for (int s2 = 128; s2 > 0; s2 >>= 1){
    if (t < s2) ra[t] += ra[t+s2];
    __syncthreads();
  }
  if (t == 0) dvec[r] = ra[0];
}

// merged: y<6 -> vecsum segment y (72 atomics over 6 addrs); y=6,7 -> diag rsqrt per side
__global__ void vsum_diag_k(const float* __restrict__ dv0, const float* __restrict__ dv1,
                            float* __restrict__ sump,
                            const float* __restrict__ sim0, const float* __restrict__ sim1,
                            float* __restrict__ rs0, float* __restrict__ rs1){
  int y = blockIdx.y;
  int t = threadIdx.x;
  if (y < 6){
    int side = y / 3, layer = y % 3;
    const float* v = (side ? dv1 : dv0) + layer*N_DRUG;
    __shared__ float red[256];
    float s = 0.f;
    for (int i = blockIdx.x*256 + t; i < N_DRUG; i += gridDim.x*256) s += v[i];
    red[t] = s; __syncthreads();
    for (int s2 = 128; s2 > 0; s2 >>= 1){ if (t < s2) red[t] += red[t+s2]; __syncthreads(); }
    if (t == 0) atomicAdd(&sump[y], red[0]);
  } else {
    int side = y - 6;
    int i = blockIdx.x*256 + t;
    const float* sim = side ? sim1 : sim0;
    float* rs = side ? rs1 : rs0;
    if (i < N_DRUG) rs[i] = rsqrtf(sim[(long)i*N_DRUG + i] + 3.0f);
  }
}

// ====================== 256x256 8-phase GEMM (TN), 2 K-tiles/iter ======================
// Partial P[z]: z<2 -> P + z*M*N ; z>=2 -> Palt + (z-2)*M*N. kz/64 MUST be even.
__global__ __launch_bounds__(512, 2) void gemm8p(
    const unsigned short* __restrict__ A, const unsigned short* __restrict__ Bt,
    float* __restrict__ P, float* __restrict__ Palt, int M, int N, int K, int kz)
{
  __shared__ unsigned short lds[2][2][16384];   // [buf][A/B][256*64]
  int t = threadIdx.x;
  int lane = t & 63, wave = t >> 6;
  int wm = wave >> 2, wn = wave & 3;

  // XCD-aware bijective swizzle (grid x*y % 8 == 0 at our launches)
  int nbx = gridDim.x;
  int nwg = nbx * gridDim.y;
  int bid = blockIdx.y * nbx + blockIdx.x;
  int cpx = nwg >> 3;
  int swz = (bid & 7) * cpx + (bid >> 3);
  long brow = (long)(swz / nbx) * 256;
  long bcol = (long)(swz % nbx) * 256;
  long k0 = (long)blockIdx.z * kz;
  int nt = kz >> 6;                             // even by construction

  // staging: one gl_lds line = 512thr x 16B = 8KB = 64 rows x 128B
  int sr = wave*8 + (lane >> 3);                // row 0..63 within line
  int cg = (lane & 7) ^ (lane >> 3);            // pre-swizzled source chunk
  const unsigned short* gA = A  + (brow + sr)*(long)K + k0 + cg*8;
  const unsigned short* gB = Bt + (bcol + sr)*(long)K + k0 + cg*8;
  unsigned ldsw = wave * 512;                   // wave-uniform dest (elems)

  auto stage = [&](int b, int mat, int h, int tk){
    const unsigned short* g = (mat ? gB : gA) + (long)(h*128)*K + (long)tk*64;
    unsigned short* d = &lds[b][mat][h*8192 + ldsw];
    gl_lds(g, d);
    gl_lds(g + (long)64*K, d + 4096);
  };

  // reader: row R, chunk c -> elem R*64 + ((c ^ (R&7))*8)
  int fr = lane & 15, q = lane >> 4;
  int lo = fr*64 + ((q ^ (fr & 7))*8);
  int dk = (lo ^ 32) - lo;                      // chunk +4 (kk=1) slot flip

  f32x4 acc[8][4];
  #pragma unroll
  for (int a = 0; a < 8; a++)
    #pragma unroll
    for (int b = 0; b < 4; b++){ acc[a][b][0]=0.f; acc[a][b][1]=0.f; acc[a][b][2]=0.f; acc[a][b][3]=0.f; }
  bf16x8 af[4][2], bf[4][2];

  const unsigned short* a0p = &lds[0][0][wm*8192 + lo];
  const unsigned short* b0p = &lds[0][1][wn*4096 + lo];
  const unsigned short* a1p = &lds[1][0][wm*8192 + lo];
  const unsigned short* b1p = &lds[1][1][wn*4096 + lo];

#define RD_AF_LO(ab) { _Pragma("unroll") for (int j = 0; j < 4; ++j){ \
    af[j][0] = *(const bf16x8*)((ab) + j*1024); af[j][1] = *(const bf16x8*)((ab) + j*1024 + dk); } }
#define RD_AF_HI(ab) { _Pragma("unroll") for (int j = 0; j < 4; ++j){ \
    af[j][0] = *(const bf16x8*)((ab) + (4+j)*1024); af[j][1] = *(const bf16x8*)((ab) + (4+j)*1024 + dk); } }
#define RD_BF_LO(bb) { _Pragma("unroll") for (int j = 0; j < 2; ++j){ \
    bf[j][0] = *(const bf16x8*)((bb) + j*1024); bf[j][1] = *(const bf16x8*)((bb) + j*1024 + dk); } }
#define RD_BF_HI(bb) { _Pragma("unroll") for (int j = 2; j < 4; ++j){ \
    bf[j][0] = *(const bf16x8*)((bb) + j*1024); bf[j][1] = *(const bf16x8*)((bb) + j*1024 + dk); } }
#define MFMA_Q(MB, NB) { __builtin_amdgcn_s_setprio(1); \
    _Pragma("unroll") for (int kk = 0; kk < 2; ++kk) \
      _Pragma("unroll") for (int mi = 0; mi < 4; ++mi) \
        _Pragma("unroll") for (int ni = (NB); ni < (NB)+2; ++ni) \
          acc[(MB)+mi][ni] = __builtin_amdgcn_mfma_f32_16x16x32_bf16(af[mi][kk], bf[ni][kk], acc[(MB)+mi][ni], 0, 0, 0); \
    __builtin_amdgcn_s_setprio(0); }

  // prologue: tile0 fully -> buf0; tile1 B-halves -> buf1 (12 loads, drain to 4)
  stage(0,0,0,0); stage(0,0,1,0); stage(0,1,0,0); stage(0,1,1,0);
  stage(1,1,0,1); stage(1,1,1,1);
  WAITVM(4);
  SYNC();

  int half = nt >> 1;
  for (int i = 0; i < half; ++i){
    int t1 = 2*i+1, t2 = 2*i+2, t3 = 2*i+3;
    bool s2 = t2 < nt, s3 = t3 < nt;
    // ===== tile 2i from buf0 =====
    RD_AF_LO(a0p); RD_BF_LO(b0p);
    stage(1,0,0,t1);
    SYNC(); MFMA_Q(0,0); SYNC();
    RD_BF_HI(b0p);
    stage(1,0,1,t1);
    SYNC(); MFMA_Q(0,2); SYNC();
    RD_AF_HI(a0p);
    if (s2) stage(0,1,0,t2);
    SYNC(); MFMA_Q(4,0); SYNC();
    if (s2){ stage(0,1,1,t2); WAITVM(4); } else { WAITVM(0); }
    SYNC(); MFMA_Q(4,2); SYNC();
    // ===== tile 2i+1 from buf1 =====
    RD_AF_LO(a1p); RD_BF_LO(b1p);
    if (s2) stage(0,0,0,t2);
    SYNC(); MFMA_Q(0,0); SYNC();
    RD_BF_HI(b1p);
    if (s2) stage(0,0,1,t2);
    SYNC(); MFMA_Q(0,2); SYNC();
    RD_AF_HI(a1p);
    if (s3) stage(1,1,0,t3);
    SYNC(); MFMA_Q(4,0); SYNC();
    if (s3){ stage(1,1,1,t3); WAITVM(4); } else { WAITVM(0); }
    SYNC(); MFMA_Q(4,2); SYNC();
  }
#undef RD_AF_LO
#undef RD_AF_HI
#undef RD_BF_LO
#undef RD_BF_HI
#undef MFMA_Q

  int z = blockIdx.z;
  float* Pz = (z < 2) ? (P + (long)z*M*N) : (Palt + (long)(z-2)*M*N);
  #pragma unroll
  for (int mi = 0; mi < 8; ++mi){
    #pragma unroll
    for (int ni = 0; ni < 4; ++ni){
      long col = bcol + wn*64 + ni*16 + fr;
      #pragma unroll
      for (int r = 0; r < 4; ++r){
        long row = brow + wm*128 + mi*16 + q*4 + r;
        Pz[row*N + col] = acc[mi][ni][r];
      }
    }
  }
}

// XWb = bf16(p0+p1+p2+p3)
__global__ void reduce4b_k(const float* __restrict__ p, unsigned short* __restrict__ outb, long n){
  long i = ((long)blockIdx.x*blockDim.x + threadIdx.x)*4;
  if (i >= n) return;
  float4 s = *(const float4*)(p + i);
  #pragma unroll
  for (int z = 1; z < 4; z++){
    float4 x = *(const float4*)(p + (long)z*n + i);
    s.x += x.x; s.y += x.y; s.z += x.z; s.w += x.w;
  }
  ushort4 o; o.x = f2b(s.x); o.y = f2b(s.y); o.z = f2b(s.z); o.w = f2b(s.w);
  *(ushort4*)(outb + i) = o;
}

// out = 0.5*(pa+pb+pc)
__global__ void reduce3h_k(const float* __restrict__ pa, const float* __restrict__ pb,
                           const float* __restrict__ pc, float* __restrict__ out, long n){
  long i = ((long)blockIdx.x*blockDim.x + threadIdx.x)*4;
  if (i >= n) return;
  float4 a = *(const float4*)(pa + i);
  float4 b = *(const float4*)(pb + i);
  float4 c = *(const float4*)(pc + i);
  float4 o;
  o.x = 0.5f*(a.x + b.x + c.x); o.y = 0.5f*(a.y + b.y + c.y);
  o.z = 0.5f*(a.z + b.z + c.z); o.w = 0.5f*(a.w + b.w + c.w);
  *(float4*)(out + i) = o;
}

// ------ bf16 MFMA GEMM (TN), BK=64, XOR-swizzled LDS, 2-phase dbuf; bf16 output ------
__global__ __launch_bounds__(256) void gemm_tn(
    const unsigned short* __restrict__ A, const unsigned short* __restrict__ Bt,
    unsigned short* __restrict__ Cb, int M, int N, int K)
{
  __shared__ unsigned short As[2][128*64];
  __shared__ unsigned short Bs[2][128*64];
  int t = threadIdx.x;
  int wave = t >> 6, lane = t & 63;
  int brow = blockIdx.y*128, bcol = blockIdx.x*128;
  int wr = (wave >> 1)*64, wc = (wave & 1)*64;
  int fr = lane & 15, q = lane >> 4;
  int rin = lane >> 3, kslot = (lane & 7) ^ rin;

  f32x4 acc[4][4];
  #pragma unroll
  for (int a = 0; a < 4; a++)
    #pragma unroll
    for (int b = 0; b < 4; b++){ acc[a][b][0]=0.f; acc[a][b][1]=0.f; acc[a][b][2]=0.f; acc[a][b][3]=0.f; }

  int aoff[4][2], boff[4][2];
  #pragma unroll
  for (int mi = 0; mi < 4; mi++){
    int row = wr + mi*16 + fr;
    #pragma unroll
    for (int kk = 0; kk < 2; kk++) aoff[mi][kk] = row*64 + (((kk*4 + q) ^ (row & 7))*8);
  }
  #pragma unroll
  for (int ni = 0; ni < 4; ni++){
    int row = wc + ni*16 + fr;
    #pragma unroll
    for (int kk = 0; kk < 2; kk++) boff[ni][kk] = row*64 + (((kk*4 + q) ^ (row & 7))*8);
  }

  auto stage = [&](int buf, int k0){
    #pragma unroll
    for (int p = 0; p < 4; p++){
      int rsec = p*32 + wave*8;
      gl_lds(A  + (long)(brow + rsec + rin)*K + k0 + kslot*8, &As[buf][rsec*64]);
      gl_lds(Bt + (long)(bcol + rsec + rin)*K + k0 + kslot*8, &Bs[buf][rsec*64]);
    }
  };

  int nsteps = K >> 6;
  stage(0, 0);
  __syncthreads();
  int curb = 0;
  for (int s = 0; s < nsteps; s++){
    if (s + 1 < nsteps) stage(curb ^ 1, (s + 1)*64);
    const unsigned short* a_l = As[curb];
    const unsigned short* b_l = Bs[curb];
    #pragma unroll
    for (int kk = 0; kk < 2; kk++){
      bf16x8 af[4], bfv[4];
      #pragma unroll
      for (int mi = 0; mi < 4; mi++) af[mi]  = *(const bf16x8*)(a_l + aoff[mi][kk]);
      #pragma unroll
      for (int ni = 0; ni < 4; ni++) bfv[ni] = *(const bf16x8*)(b_l + boff[ni][kk]);
      #pragma unroll
      for (int mi = 0; mi < 4; mi++)
        #pragma unroll
        for (int ni = 0; ni < 4; ni++)
          acc[mi][ni] = __builtin_amdgcn_mfma_f32_16x16x32_bf16(af[mi], bfv[ni], acc[mi][ni], 0, 0, 0);
    }
    __syncthreads();
    curb ^= 1;
  }

  #pragma unroll
  for (int mi = 0; mi < 4; mi++){
    #pragma unroll
    for (int ni = 0; ni < 4; ni++){
      int col = bcol + wc + ni*16 + fr;
      #pragma unroll
      for (int r = 0; r < 4; r++){
        int row = brow + wr + mi*16 + q*4 + r;
        Cb[(long)row*N + col] = f2b(acc[mi][ni][r]);
      }
    }
  }
}

// ---------------- fused 3-layer GIP GEMM (both sides, z=2), dbuf ----------------
// epilogue: arg_l = c_l*S_l + b_l (one FMA) + v_exp_f32 (2^x) per layer
__global__ __launch_bounds__(512) void gip_gemm(
    const unsigned short* __restrict__ Y0, const unsigned short* __restrict__ Y1,
    const float* __restrict__ sim0, const float* __restrict__ sim1,
    const float* __restrict__ dva, const float* __restrict__ dvb,
    const float* __restrict__ sumps,
    const float* __restrict__ rs0, const float* __restrict__ rs1,
    unsigned short* __restrict__ o0, unsigned short* __restrict__ o1)
{
  __shared__ unsigned short As[2][128*64];
  __shared__ unsigned short Bs[2][128*64];
  const int K = 896;
  int side = blockIdx.z;
  const unsigned short* Y = side ? Y1 : Y0;
  const float* sim  = side ? sim1 : sim0;
  const float* dv   = side ? dvb : dva;
  const float* sums = sumps + side*3;
  const float* rs   = side ? rs1 : rs0;
  unsigned short* outp = side ? o1 : o0;
  int outoff = side ? N_DRUG : 0;

  int t = threadIdx.x;
  int wave = t >> 6, lane = t & 63;
  int brow = blockIdx.y*128, bcol = blockIdx.x*128;
  int wr = (wave >> 1)*32, wc = (wave & 1)*64;
  int fr = lane & 15, q = lane >> 4;
  int rin = lane >> 3, kslot = (lane & 7) ^ rin;

  f32x4 acc0[2][4], acc1[2][4], acc2[2][4];
  #pragma unroll
  for (int a = 0; a < 2; a++)
    #pragma unroll
    for (int b = 0; b < 4; b++){
      acc0[a][b][0]=0.f;acc0[a][b][1]=0.f;acc0[a][b][2]=0.f;acc0[a][b][3]=0.f;
      acc1[a][b][0]=0.f;acc1[a][b][1]=0.f;acc1[a][b][2]=0.f;acc1[a][b][3]=0.f;
      acc2[a][b][0]=0.f;acc2[a][b][1]=0.f;acc2[a][b][2]=0.f;acc2[a][b][3]=0.f;
    }

  int aoff[2][2], boff[4][2];
  #pragma unroll
  for (int mi = 0; mi < 2; mi++){
    int row = wr + mi*16 + fr;
    #pragma unroll
    for (int kk = 0; kk < 2; kk++) aoff[mi][kk] = row*64 + (((kk*4 + q) ^ (row & 7))*8);
  }
  #pragma unroll
  for (int ni = 0; ni < 4; ni++){
    int row = wc + ni*16 + fr;
    #pragma unroll
    for (int kk = 0; kk < 2; kk++) boff[ni][kk] = row*64 + (((kk*4 + q) ^ (row & 7))*8);
  }

  auto stage = [&](int buf, int k0){
    #pragma unroll
    for (int p = 0; p < 2; p++){
      int rsec = p*64 + wave*8;
      gl_lds(Y + (long)(brow + rsec + rin)*K + k0 + kslot*8, &As[buf][rsec*64]);
      gl_lds(Y + (long)(bcol + rsec + rin)*K + k0 + kslot*8, &Bs[buf][rsec*64]);
    }
  };

  int curb = 0, s = 0;
  stage(0, 0);
  __syncthreads();

#define GSTEP(ACC) { \
    if (s + 1 < 14) stage(curb ^ 1, (s + 1)*64); \
    const unsigned short* a_l = As[curb]; \
    const unsigned short* b_l = Bs[curb]; \
    _Pragma("unroll") \
    for (int kk = 0; kk < 2; kk++){ \
      bf16x8 af0 = *(const bf16x8*)(a_l + aoff[0][kk]); \
      bf16x8 af1 = *(const bf16x8*)(a_l + aoff[1][kk]); \
      _Pragma("unroll") \
      for (int ni = 0; ni < 4; ni++){ \
        bf16x8 bv = *(const bf16x8*)(b_l + boff[ni][kk]); \
        ACC[0][ni] = __builtin_amdgcn_mfma_f32_16x16x32_bf16(af0, bv, ACC[0][ni], 0, 0, 0); \
        ACC[1][ni] = __builtin_amdgcn_mfma_f32_16x16x32_bf16(af1, bv, ACC[1][ni], 0, 0, 0); \
      } \
    } \
    __syncthreads(); curb ^= 1; s++; }

  for (int i = 0; i < 8; i++) GSTEP(acc0)
  for (int i = 0; i < 4; i++) GSTEP(acc1)
  for (int i = 0; i < 2; i++) GSTEP(acc2)
#undef GSTEP

  // h_l = GAMMA*im_l*log2e ; arg_l = 2*h_l*S_l - h_l*(d_row + d_col)
  float h0 = GAMMA * ((float)N_DRUG / sums[0]) * LOG2E;
  float h1 = GAMMA * ((float)N_DRUG / sums[1]) * LOG2E;
  float h2 = GAMMA * ((float)N_DRUG / sums[2]) * LOG2E;
  float c0 = 2.f*h0, c1 = 2.f*h1, c2 = 2.f*h2;
  #pragma unroll
  for (int mi = 0; mi < 2; mi++){
    #pragma unroll
    for (int ni = 0; ni < 4; ni++){
      int col = bcol + wc + ni*16 + fr;
      float d0c = dv[col], d1c = dv[N_DRUG + col], d2c = dv[2*N_DRUG + col];
      float rc = rs[col];
      #pragma unroll
      for (int r = 0; r < 4; r++){
        int row = brow + wr + mi*16 + q*4 + r;
        float b0 = -h0*(dv[row] + d0c);
        float b1 = -h1*(dv[N_DRUG + row] + d1c);
        float b2 = -h2*(dv[2*N_DRUG + row] + d2c);
        float v = sim[(long)row*N_DRUG + col]
                + fexp2(fmaf(c0, acc0[mi][ni][r], b0))
                + fexp2(fmaf(c1, acc1[mi][ni][r], b1))
                + fexp2(fmaf(c2, acc2[mi][ni][r], b2));
        outp[(long)row*N_NODES + outoff + col] = f2b(v * rs[row] * rc);
      }
    }
  }
}

// ---------------- host ----------------
extern "C" void kernel_launch(void* const* d_in, const int* in_sizes, int n_in,
                              void* d_out, int out_size, void* d_ws, size_t ws_size,
                              hipStream_t stream){
  const float* x        = (const float*)d_in[0];
  const int*   ei       = (const int*)d_in[1];
  const float* adj      = (const float*)d_in[2];
  const float* drug_sim = (const float*)d_in[3];
  const float* dis_sim  = (const float*)d_in[4];
  const float* alpha1   = (const float*)d_in[5];
  const float* alpha2   = (const float*)d_in[6];
  const float* W[3]   = {(const float*)d_in[7],  (const float*)d_in[11], (const float*)d_in[15]};
  const float* as_[3] = {(const float*)d_in[8],  (const float*)d_in[12], (const float*)d_in[16]};
  const float* ad_[3] = {(const float*)d_in[9],  (const float*)d_in[13], (const float*)d_in[17]};
  const float* bs_[3] = {(const float*)d_in[10], (const float*)d_in[14], (const float*)d_in[18]};
  float* out = (float*)d_out;
  const int Fs[3] = {512, 256, 128};

  char* p = (char*)d_ws;
  auto alloc = [&](size_t bytes)->char*{
    char* r = p; p += (bytes + 255) & ~(size_t)255; return r;
  };
  unsigned short* xb  = (unsigned short*)alloc((size_t)N_NODES*N_NODES*2);
  // region wb..ycat0 is contiguous and fully dead by final-GEMM time -> hosts partial z=2
  unsigned short* wb  = (unsigned short*)alloc((size_t)N_NODES*512*2);
  unsigned short* XWb = (unsigned short*)alloc((size_t)N_NODES*512*2);
  unsigned short* HbL[3];
  HbL[0] = (unsigned short*)alloc((size_t)N_NODES*512*2);
  HbL[1] = (unsigned short*)alloc((size_t)N_NODES*256*2);
  HbL[2] = (unsigned short*)alloc((size_t)N_NODES*128*2);
  float* es    = (float*)alloc(N_NODES*4);
  float* edv   = (float*)alloc(N_NODES*4);
  float* denom = (float*)alloc(N_NODES*4);
  float* exc   = (float*)alloc((size_t)E_TOT*4);
  int* cntcur  = (int*)alloc((size_t)2*N_NODES*4);
  int* cnt = cntcur, *cur = cntcur + N_NODES;
  int* cptr = (int*)alloc((N_NODES+1)*4);
  int* srcs  = (int*)alloc((size_t)E_TOT*4);
  int* dsts  = (int*)alloc((size_t)E_TOT*4);
  float* wcsr = (float*)alloc((size_t)E_TOT*4);
  unsigned short* ycat[2];
  ycat[0] = (unsigned short*)alloc((size_t)N_DRUG*896*2);
  ycat[1] = (unsigned short*)alloc((size_t)N_DRUG*896*2);
  float* dvv[2];
  dvv[0] = (float*)alloc((size_t)3*N_DRUG*4);
  dvv[1] = (float*)alloc((size_t)3*N_DRUG*4);
  float* sump = (float*)alloc(256);
  float* rsv[2];
  rsv[0] = (float*)alloc(N_DRUG*4);
  rsv[1] = (float*)alloc(N_DRUG*4);
  unsigned short* Abuf  = (unsigned short*)alloc((size_t)N_DRUG*N_NODES*2);
  unsigned short* Btbuf = (unsigned short*)alloc((size_t)N_DRUG*N_NODES*2);

  // split-K partials for layer-1 live in dead Abuf+Btbuf space
  float* pL1 = (float*)Abuf;
  // final-GEMM partials: z=0,1 in dead xb (exactly 2x 37.7MB); z=2 in dead wb..ycat0 span
  float* pF01 = (float*)xb;
  float* pF2  = (float*)wb;
  const long MN = (long)N_DRUG*N_DRUG;

  // --- prep: x cast, CSR build (+ one-time adj gather into CSR order) ---
  cast_bf16_k<<<4096, 256, 0, stream>>>(x, xb, (long)N_NODES*N_NODES);
  hipMemsetAsync(cntcur, 0, (size_t)2*N_NODES*4, stream);
  hist_k<<<(E_TOT+255)/256, 256, 0, stream>>>(ei, cnt);
  scan_k<<<1, 1024, 0, stream>>>(cnt, cptr);
  scatter_k<<<(E_TOT+255)/256, 256, 0, stream>>>(ei, adj, cptr, cur, srcs, dsts, wcsr);

  // --- 3 GAT layers ---
  const unsigned short* Ain = xb;
  int Kin = N_NODES;
  for (int l = 0; l < 3; l++){
    int F = Fs[l];
    tcast_k<<<dim3(F/32, Kin/32), dim3(32,8), 0, stream>>>(W[l], wb, Kin, F, Kin, 0);
    if (l == 0){
      gemm8p<<<dim3(F/256, N_NODES/256, 4), 512, 0, stream>>>(Ain, wb, pL1, pL1 + 2*(long)N_NODES*F, N_NODES, F, Kin, Kin/4);
      reduce4b_k<<<(int)(((long)N_NODES*F/4 + 255)/256), 256, 0, stream>>>(pL1, XWb, (long)N_NODES*F);
    } else {
      gemm_tn<<<dim3(F/128, N_NODES/128), 256, 0, stream>>>(Ain, wb, XWb, N_NODES, F, Kin);
    }
    dots_k<<<N_NODES, 64, 0, stream>>>(XWb, as_[l], ad_[l], es, edv, denom, F);
    phase12_k<<<(E_TOT+255)/256, 256, 0, stream>>>(srcs, dsts, wcsr, es, edv, exc, denom);
    if (F >= 256)
      agg4_k<<<N_NODES, F/4, 0, stream>>>(XWb, cptr, srcs, exc, denom, bs_[l], HbL[l], F);
    else
      agg_k<<<N_NODES, 64, 0, stream>>>(XWb, cptr, srcs, exc, denom, bs_[l], HbL[l], F);
    Ain = HbL[l]; Kin = F;
  }

  // --- GIP prep ---
  hipMemsetAsync(sump, 0, 24, stream);
  rownorm_all_k<<<dim3(N_DRUG, 6), 256, 0, stream>>>(HbL[0], HbL[1], HbL[2],
                                                     ycat[0], ycat[1], dvv[0], dvv[1]);
  vsum_diag_k<<<dim3(12, 8), 256, 0, stream>>>(dvv[0], dvv[1], sump,
                                               drug_sim, dis_sim, rsv[0], rsv[1]);

  // --- alpha transposes into concat buffers (merged z=2) ---
  // Abuf = [NK_drug | alpha2^T], Btbuf = [alpha1^T | NK_dis]
  tcast2_k<<<dim3(N_DRUG/32, N_DRUG/32, 2), dim3(32,8), 0, stream>>>(alpha2, alpha1, Abuf, Btbuf);

  // --- fused GIP -> normalized kernel (bf16), both sides in one launch ---
  gip_gemm<<<dim3(N_DRUG/128, N_DRUG/128, 2), 512, 0, stream>>>(
      ycat[0], ycat[1], drug_sim, dis_sim, dvv[0], dvv[1], sump, rsv[0], rsv[1], Abuf, Btbuf);

  // --- final: out = 0.5*(NK1@a1 + a2^T@NK2), K=6144, split-K x3 (kz=2048, nt=32) ---
  gemm8p<<<dim3(N_DRUG/256, N_DRUG/256, 3), 512, 0, stream>>>(Abuf, Btbuf, pF01, pF2, N_DRUG, N_DRUG, N_NODES, N_NODES/3);
  reduce3h_k<<<(int)((MN/4 + 255)/256), 256, 0, stream>>>(pF01, pF01 + MN, pF2, out, MN);

  (void)in_sizes; (void)n_in; (void)out_size; (void)ws_size;
}

// Round 14
// 561.987 us; speedup vs baseline: 1.1240x; 1.1240x over previous
//
#include <hip/hip_runtime.h>
#include <hip/hip_bf16.h>
#include <stdint.h>

#define N_NODES 6144
#define N_DRUG  3072
#define N_EDGE  196608
#define E_TOT   (N_EDGE + N_NODES)
#define GAMMA   0.03125f
#define LOG2E   1.44269504f

typedef __bf16 bf16x8 __attribute__((ext_vector_type(8)));
typedef float  f32x4  __attribute__((ext_vector_type(4)));

__device__ __forceinline__ unsigned short f2b(float f){
  union { float f; unsigned u; } v; v.f = f;
  unsigned r = v.u + 0x7FFFu + ((v.u >> 16) & 1u);
  return (unsigned short)(r >> 16);
}
__device__ __forceinline__ float b2f(unsigned short b){
  union { unsigned u; float f; } v; v.u = ((unsigned)b) << 16;
  return v.f;
}
__device__ __forceinline__ float fexp2(float x){
  float r; asm("v_exp_f32 %0, %1" : "=v"(r) : "v"(x)); return r;
}
__device__ __forceinline__ void gl_lds(const void* g, void* l){
  __builtin_amdgcn_global_load_lds((const __attribute__((address_space(1))) void*)g,
                                   (__attribute__((address_space(3))) void*)l, 16, 0, 0);
}

#define WAITVM(N) asm volatile("s_waitcnt vmcnt(" #N ")" ::: "memory")
#define SYNC() { __builtin_amdgcn_sched_barrier(0); __builtin_amdgcn_s_barrier(); __builtin_amdgcn_sched_barrier(0); }

// ---------------- elementwise / transpose casts ----------------
__global__ void cast_bf16_k(const float* __restrict__ in, unsigned short* __restrict__ out, long n){
  long i = ((long)blockIdx.x*blockDim.x + threadIdx.x)*4;
  long stride = (long)gridDim.x*blockDim.x*4;
  for (; i < n; i += stride){
    float4 v = *(const float4*)(in + i);
    ushort4 o;
    o.x = f2b(v.x); o.y = f2b(v.y); o.z = f2b(v.z); o.w = f2b(v.w);
    *(ushort4*)(out + i) = o;
  }
}

// out[c][OLD] at [c][OOFF + r] = bf16(in[r][c]); in is [R][Cd]
__global__ void tcast_k(const float* __restrict__ in, unsigned short* __restrict__ out,
                        int R, int Cd, int OLD, int OOFF){
  __shared__ float tile[32][33];
  int bx = blockIdx.x*32, by = blockIdx.y*32;
  int tx = threadIdx.x, ty = threadIdx.y;
  for (int i = ty; i < 32; i += 8) tile[i][tx] = in[(long)(by+i)*Cd + bx + tx];
  __syncthreads();
  for (int i = ty; i < 32; i += 8) out[(long)(bx+i)*OLD + OOFF + by + tx] = f2b(tile[tx][i]);
}

// z=0: alpha2 -> o0 at OOFF=N_DRUG ; z=1: alpha1 -> o1 at OOFF=0  (both 3072^2, OLD=N_NODES)
__global__ void tcast2_k(const float* __restrict__ a2, const float* __restrict__ a1,
                         unsigned short* __restrict__ o0, unsigned short* __restrict__ o1){
  __shared__ float tile[32][33];
  const float* in = blockIdx.z ? a1 : a2;
  unsigned short* out = blockIdx.z ? o1 : o0;
  int OOFF = blockIdx.z ? 0 : N_DRUG;
  int bx = blockIdx.x*32, by = blockIdx.y*32;
  int tx = threadIdx.x, ty = threadIdx.y;
  for (int i = ty; i < 32; i += 8) tile[i][tx] = in[(long)(by+i)*N_DRUG + bx + tx];
  __syncthreads();
  for (int i = ty; i < 32; i += 8) out[(long)(bx+i)*N_NODES + OOFF + by + tx] = f2b(tile[tx][i]);
}

// ---------------- CSR build ----------------
__global__ void hist_k(const int* __restrict__ ei, int* __restrict__ cnt){
  int i = blockIdx.x*blockDim.x + threadIdx.x;
  if (i >= E_TOT) return;
  int d = (i < N_EDGE) ? ei[N_EDGE + i] : (i - N_EDGE);
  atomicAdd(&cnt[d], 1);
}

__global__ void scan_k(const int* __restrict__ cnt, int* __restrict__ ptr){
  __shared__ int sums[1024];
  int t = threadIdx.x;
  int v[6]; int s = 0;
  #pragma unroll
  for (int i = 0; i < 6; i++){ v[i] = s; s += cnt[t*6 + i]; }
  sums[t] = s; __syncthreads();
  for (int off = 1; off < 1024; off <<= 1){
    int add = (t >= off) ? sums[t - off] : 0;
    __syncthreads();
    sums[t] += add;
    __syncthreads();
  }
  int base = (t == 0) ? 0 : sums[t-1];
  #pragma unroll
  for (int i = 0; i < 6; i++) ptr[t*6 + i] = base + v[i];
  if (t == 1023) ptr[N_NODES] = sums[1023];
}

// one-time: CSR scatter + adj gather into CSR order (layer-invariant edge weights)
__global__ void scatter_k(const int* __restrict__ ei, const float* __restrict__ adj,
                          const int* __restrict__ ptr, int* __restrict__ cur,
                          int* __restrict__ srcs, int* __restrict__ dsts,
                          float* __restrict__ wcsr){
  int i = blockIdx.x*blockDim.x + threadIdx.x;
  if (i >= E_TOT) return;
  int s = (i < N_EDGE) ? ei[i] : (i - N_EDGE);
  int d = (i < N_EDGE) ? ei[N_EDGE + i] : (i - N_EDGE);
  int pos = ptr[d] + atomicAdd(&cur[d], 1);
  srcs[pos] = s; dsts[pos] = d;
  wcsr[pos] = (i < N_EDGE) ? adj[(long)s*N_NODES + d] : 1.0f;
}

// ---------------- GAT pieces ----------------
// reads bf16 XWb via ushort4
__global__ void dots_k(const unsigned short* __restrict__ XWb, const float* __restrict__ av,
                       const float* __restrict__ dv, float* __restrict__ es,
                       float* __restrict__ ed, int F){
  int n = blockIdx.x, l = threadIdx.x;
  float s = 0.f, d = 0.f;
  for (int f = l*4; f < F; f += 256){
    ushort4 u = *(const ushort4*)(XWb + (long)n*F + f);
    float4 a = *(const float4*)(av + f);
    float4 dd = *(const float4*)(dv + f);
    s += b2f(u.x)*a.x + b2f(u.y)*a.y + b2f(u.z)*a.z + b2f(u.w)*a.w;
    d += b2f(u.x)*dd.x + b2f(u.y)*dd.y + b2f(u.z)*dd.z + b2f(u.w)*dd.w;
  }
  #pragma unroll
  for (int off = 32; off > 0; off >>= 1){ s += __shfl_down(s, off); d += __shfl_down(d, off); }
  if (l == 0){ es[n] = s; ed[n] = d; }
}

// pure streaming: no atomics (denom computed inline by agg)
__global__ void phase12_k(const int* __restrict__ srcs, const int* __restrict__ dsts,
                          const float* __restrict__ wcsr,
                          const float* __restrict__ es, const float* __restrict__ ed,
                          float* __restrict__ exc){
  int p = blockIdx.x*blockDim.x + threadIdx.x;
  if (p >= E_TOT) return;
  int s = srcs[p], d = dsts[p];
  float e = es[s] + ed[d];
  e = (e > 0.f) ? e : 0.2f*e;
  exc[p] = fexp2(e * LOG2E) * wcsr[p];
}

// one block per node; blockDim = F/4; ushort4 gathers; denom accumulated in-register
__global__ void agg4_k(const unsigned short* __restrict__ XWb, const int* __restrict__ ptr,
                       const int* __restrict__ srcs, const float* __restrict__ exc,
                       const float* __restrict__ bias,
                       unsigned short* __restrict__ Hb, int F){
  int n = blockIdx.x, t = threadIdx.x;
  int st = ptr[n], en = ptr[n+1];
  float a0v = 0.f, a1v = 0.f, a2v = 0.f, a3v = 0.f, dsum = 0.f;
  int j = st;
  for (; j + 1 < en; j += 2){
    float w0 = exc[j], w1 = exc[j+1];
    int s0 = srcs[j], s1 = srcs[j+1];
    ushort4 u0 = *(const ushort4*)(XWb + (long)s0*F + t*4);
    ushort4 u1 = *(const ushort4*)(XWb + (long)s1*F + t*4);
    dsum += w0 + w1;
    a0v += w0*b2f(u0.x) + w1*b2f(u1.x); a1v += w0*b2f(u0.y) + w1*b2f(u1.y);
    a2v += w0*b2f(u0.z) + w1*b2f(u1.z); a3v += w0*b2f(u0.w) + w1*b2f(u1.w);
  }
  if (j < en){
    float w0 = exc[j]; int s0 = srcs[j];
    ushort4 u0 = *(const ushort4*)(XWb + (long)s0*F + t*4);
    dsum += w0;
    a0v += w0*b2f(u0.x); a1v += w0*b2f(u0.y); a2v += w0*b2f(u0.z); a3v += w0*b2f(u0.w);
  }
  float invd = 1.f/(dsum + 1e-16f);
  float4 b = *(const float4*)(bias + t*4);
  ushort4 ob;
  ob.x = f2b(fmaxf(a0v*invd + b.x, 0.f)); ob.y = f2b(fmaxf(a1v*invd + b.y, 0.f));
  ob.z = f2b(fmaxf(a2v*invd + b.z, 0.f)); ob.w = f2b(fmaxf(a3v*invd + b.w, 0.f));
  *(ushort4*)(Hb + (long)n*F + t*4) = ob;
}

// F = 128 variant: blockDim = 64, ushort2 per thread
__global__ void agg_k(const unsigned short* __restrict__ XWb, const int* __restrict__ ptr,
                      const int* __restrict__ srcs, const float* __restrict__ exc,
                      const float* __restrict__ bias,
                      unsigned short* __restrict__ Hb, int F){
  int n = blockIdx.x, t = threadIdx.x;
  int st = ptr[n], en = ptr[n+1];
  float ax = 0.f, ay = 0.f, dsum = 0.f;
  int j = st;
  for (; j + 1 < en; j += 2){
    float a0 = exc[j], a1 = exc[j+1];
    int s0 = srcs[j], s1 = srcs[j+1];
    ushort2 u0 = *(const ushort2*)(XWb + (long)s0*F + t*2);
    ushort2 u1 = *(const ushort2*)(XWb + (long)s1*F + t*2);
    dsum += a0 + a1;
    ax += a0*b2f(u0.x) + a1*b2f(u1.x);
    ay += a0*b2f(u0.y) + a1*b2f(u1.y);
  }
  if (j < en){
    float a = exc[j]; int s = srcs[j];
    ushort2 u = *(const ushort2*)(XWb + (long)s*F + t*2);
    dsum += a;
    ax += a*b2f(u.x); ay += a*b2f(u.y);
  }
  float invd = 1.f/(dsum + 1e-16f);
  float2 b = *(const float2*)(bias + t*2);
  ushort2 o;
  o.x = f2b(fmaxf(ax*invd + b.x, 0.f));
  o.y = f2b(fmaxf(ay*invd + b.y, 0.f));
  *(ushort2*)(Hb + (long)n*F + t*2) = o;
}

// ---------------- GIP prep (merged over 6 segments: seg = side*3 + layer) ------
__global__ void rownorm_all_k(const unsigned short* __restrict__ H0, const unsigned short* __restrict__ H1,
                              const unsigned short* __restrict__ H2,
                              unsigned short* __restrict__ y0, unsigned short* __restrict__ y1,
                              float* __restrict__ dv0, float* __restrict__ dv1){
  int seg = blockIdx.y;
  int side = seg / 3, layer = seg % 3;
  int F = 512 >> layer;
  const unsigned short* H = (layer == 0) ? H0 : (layer == 1) ? H1 : H2;
  H += (size_t)(side ? N_DRUG : 0) * F;
  unsigned short* yb = ((side ? y1 : y0) + ((layer == 0) ? 0 : (layer == 1) ? 512 : 768));
  float* dvec = (side ? dv1 : dv0) + layer*N_DRUG;

  int r = blockIdx.x, t = threadIdx.x;
  __shared__ float ra[256], rb[256];
  float mn = 3.4e38f, mx = -3.4e38f;
  for (int f = t; f < F; f += 256){
    float v = b2f(H[(long)r*F + f]);
    mn = fminf(mn, v); mx = fmaxf(mx, v);
  }
  ra[t] = mn; rb[t] = mx; __syncthreads();
  for (int s2 = 128; s2 > 0; s2 >>= 1){
    if (t < s2){ ra[t] = fminf(ra[t], ra[t+s2]); rb[t] = fmaxf(rb[t], rb[t+s2]); }
    __syncthreads();
  }
  mn = ra[0]; mx = rb[0];
  __syncthreads();
  float sc = 1.f/(mx - mn + 1e-12f);
  float s = 0.f;
  for (int f = t; f < F; f += 256){
    float v = (b2f(H[(long)r*F + f]) - mn)*sc;
    unsigned short b = f2b(v);
    yb[(long)r*896 + f] = b;
    float vb = b2f(b);
    s += vb*vb;
  }
  ra[t] = s; __syncthreads();
  for (int s2 = 128; s2 > 0; s2 >>= 1){
    if (t < s2) ra[t] += ra[t+s2];
    __syncthreads();
  }
  if (t == 0) dvec[r] = ra[0];
}

// merged: y<6 -> vecsum segment y (72 atomics over 6 addrs); y=6,7 -> diag rsqrt per side
__global__ void vsum_diag_k(const float* __restrict__ dv0, const float* __restrict__ dv1,
                            float* __restrict__ sump,
                            const float* __restrict__ sim0, const float* __restrict__ sim1,
                            float* __restrict__ rs0, float* __restrict__ rs1){
  int y = blockIdx.y;
  int t = threadIdx.x;
  if (y < 6){
    int side = y / 3, layer = y % 3;
    const float* v = (side ? dv1 : dv0) + layer*N_DRUG;
    __shared__ float red[256];
    float s = 0.f;
    for (int i = blockIdx.x*256 + t; i < N_DRUG; i += gridDim.x*256) s += v[i];
    red[t] = s; __syncthreads();
    for (int s2 = 128; s2 > 0; s2 >>= 1){ if (t < s2) red[t] += red[t+s2]; __syncthreads(); }
    if (t == 0) atomicAdd(&sump[y], red[0]);
  } else {
    int side = y - 6;
    int i = blockIdx.x*256 + t;
    const float* sim = side ? sim1 : sim0;
    float* rs = side ? rs1 : rs0;
    if (i < N_DRUG) rs[i] = rsqrtf(sim[(long)i*N_DRUG + i] + 3.0f);
  }
}

// ====================== 256x256 8-phase GEMM (TN), 2 K-tiles/iter ======================
// Partial P[z]: z<2 -> P + z*M*N ; z>=2 -> Palt + (z-2)*M*N. kz/64 MUST be even.
__global__ __launch_bounds__(512, 2) void gemm8p(
    const unsigned short* __restrict__ A, const unsigned short* __restrict__ Bt,
    float* __restrict__ P, float* __restrict__ Palt, int M, int N, int K, int kz)
{
  __shared__ unsigned short lds[2][2][16384];   // [buf][A/B][256*64]
  int t = threadIdx.x;
  int lane = t & 63, wave = t >> 6;
  int wm = wave >> 2, wn = wave & 3;

  // XCD-aware bijective swizzle (grid x*y % 8 == 0 at our launches)
  int nbx = gridDim.x;
  int nwg = nbx * gridDim.y;
  int bid = blockIdx.y * nbx + blockIdx.x;
  int cpx = nwg >> 3;
  int swz = (bid & 7) * cpx + (bid >> 3);
  long brow = (long)(swz / nbx) * 256;
  long bcol = (long)(swz % nbx) * 256;
  long k0 = (long)blockIdx.z * kz;
  int nt = kz >> 6;                             // even by construction

  // staging: one gl_lds line = 512thr x 16B = 8KB = 64 rows x 128B
  int sr = wave*8 + (lane >> 3);                // row 0..63 within line
  int cg = (lane & 7) ^ (lane >> 3);            // pre-swizzled source chunk
  const unsigned short* gA = A  + (brow + sr)*(long)K + k0 + cg*8;
  const unsigned short* gB = Bt + (bcol + sr)*(long)K + k0 + cg*8;
  unsigned ldsw = wave * 512;                   // wave-uniform dest (elems)

  auto stage = [&](int b, int mat, int h, int tk){
    const unsigned short* g = (mat ? gB : gA) + (long)(h*128)*K + (long)tk*64;
    unsigned short* d = &lds[b][mat][h*8192 + ldsw];
    gl_lds(g, d);
    gl_lds(g + (long)64*K, d + 4096);
  };

  // reader: row R, chunk c -> elem R*64 + ((c ^ (R&7))*8)
  int fr = lane & 15, q = lane >> 4;
  int lo = fr*64 + ((q ^ (fr & 7))*8);
  int dk = (lo ^ 32) - lo;                      // chunk +4 (kk=1) slot flip

  f32x4 acc[8][4];
  #pragma unroll
  for (int a = 0; a < 8; a++)
    #pragma unroll
    for (int b = 0; b < 4; b++){ acc[a][b][0]=0.f; acc[a][b][1]=0.f; acc[a][b][2]=0.f; acc[a][b][3]=0.f; }
  bf16x8 af[4][2], bf[4][2];

  const unsigned short* a0p = &lds[0][0][wm*8192 + lo];
  const unsigned short* b0p = &lds[0][1][wn*4096 + lo];
  const unsigned short* a1p = &lds[1][0][wm*8192 + lo];
  const unsigned short* b1p = &lds[1][1][wn*4096 + lo];

#define RD_AF_LO(ab) { _Pragma("unroll") for (int j = 0; j < 4; ++j){ \
    af[j][0] = *(const bf16x8*)((ab) + j*1024); af[j][1] = *(const bf16x8*)((ab) + j*1024 + dk); } }
#define RD_AF_HI(ab) { _Pragma("unroll") for (int j = 0; j < 4; ++j){ \
    af[j][0] = *(const bf16x8*)((ab) + (4+j)*1024); af[j][1] = *(const bf16x8*)((ab) + (4+j)*1024 + dk); } }
#define RD_BF_LO(bb) { _Pragma("unroll") for (int j = 0; j < 2; ++j){ \
    bf[j][0] = *(const bf16x8*)((bb) + j*1024); bf[j][1] = *(const bf16x8*)((bb) + j*1024 + dk); } }
#define RD_BF_HI(bb) { _Pragma("unroll") for (int j = 2; j < 4; ++j){ \
    bf[j][0] = *(const bf16x8*)((bb) + j*1024); bf[j][1] = *(const bf16x8*)((bb) + j*1024 + dk); } }
#define MFMA_Q(MB, NB) { __builtin_amdgcn_s_setprio(1); \
    _Pragma("unroll") for (int kk = 0; kk < 2; ++kk) \
      _Pragma("unroll") for (int mi = 0; mi < 4; ++mi) \
        _Pragma("unroll") for (int ni = (NB); ni < (NB)+2; ++ni) \
          acc[(MB)+mi][ni] = __builtin_amdgcn_mfma_f32_16x16x32_bf16(af[mi][kk], bf[ni][kk], acc[(MB)+mi][ni], 0, 0, 0); \
    __builtin_amdgcn_s_setprio(0); }

  // prologue: tile0 fully -> buf0; tile1 B-halves -> buf1 (12 loads, drain to 4)
  stage(0,0,0,0); stage(0,0,1,0); stage(0,1,0,0); stage(0,1,1,0);
  stage(1,1,0,1); stage(1,1,1,1);
  WAITVM(4);
  SYNC();

  int half = nt >> 1;
  for (int i = 0; i < half; ++i){
    int t1 = 2*i+1, t2 = 2*i+2, t3 = 2*i+3;
    bool s2 = t2 < nt, s3 = t3 < nt;
    // ===== tile 2i from buf0 =====
    RD_AF_LO(a0p); RD_BF_LO(b0p);
    stage(1,0,0,t1);
    SYNC(); MFMA_Q(0,0); SYNC();
    RD_BF_HI(b0p);
    stage(1,0,1,t1);
    SYNC(); MFMA_Q(0,2); SYNC();
    RD_AF_HI(a0p);
    if (s2) stage(0,1,0,t2);
    SYNC(); MFMA_Q(4,0); SYNC();
    if (s2){ stage(0,1,1,t2); WAITVM(4); } else { WAITVM(0); }
    SYNC(); MFMA_Q(4,2); SYNC();
    // ===== tile 2i+1 from buf1 =====
    RD_AF_LO(a1p); RD_BF_LO(b1p);
    if (s2) stage(0,0,0,t2);
    SYNC(); MFMA_Q(0,0); SYNC();
    RD_BF_HI(b1p);
    if (s2) stage(0,0,1,t2);
    SYNC(); MFMA_Q(0,2); SYNC();
    RD_AF_HI(a1p);
    if (s3) stage(1,1,0,t3);
    SYNC(); MFMA_Q(4,0); SYNC();
    if (s3){ stage(1,1,1,t3); WAITVM(4); } else { WAITVM(0); }
    SYNC(); MFMA_Q(4,2); SYNC();
  }
#undef RD_AF_LO
#undef RD_AF_HI
#undef RD_BF_LO
#undef RD_BF_HI
#undef MFMA_Q

  int z = blockIdx.z;
  float* Pz = (z < 2) ? (P + (long)z*M*N) : (Palt + (long)(z-2)*M*N);
  #pragma unroll
  for (int mi = 0; mi < 8; ++mi){
    #pragma unroll
    for (int ni = 0; ni < 4; ++ni){
      long col = bcol + wn*64 + ni*16 + fr;
      #pragma unroll
      for (int r = 0; r < 4; ++r){
        long row = brow + wm*128 + mi*16 + q*4 + r;
        Pz[row*N + col] = acc[mi][ni][r];
      }
    }
  }
}

// XWb = bf16(p0+p1+p2+p3)
__global__ void reduce4b_k(const float* __restrict__ p, unsigned short* __restrict__ outb, long n){
  long i = ((long)blockIdx.x*blockDim.x + threadIdx.x)*4;
  if (i >= n) return;
  float4 s = *(const float4*)(p + i);
  #pragma unroll
  for (int z = 1; z < 4; z++){
    float4 x = *(const float4*)(p + (long)z*n + i);
    s.x += x.x; s.y += x.y; s.z += x.z; s.w += x.w;
  }
  ushort4 o; o.x = f2b(s.x); o.y = f2b(s.y); o.z = f2b(s.z); o.w = f2b(s.w);
  *(ushort4*)(outb + i) = o;
}

// out = 0.5*(pa+pb+pc)
__global__ void reduce3h_k(const float* __restrict__ pa, const float* __restrict__ pb,
                           const float* __restrict__ pc, float* __restrict__ out, long n){
  long i = ((long)blockIdx.x*blockDim.x + threadIdx.x)*4;
  if (i >= n) return;
  float4 a = *(const float4*)(pa + i);
  float4 b = *(const float4*)(pb + i);
  float4 c = *(const float4*)(pc + i);
  float4 o;
  o.x = 0.5f*(a.x + b.x + c.x); o.y = 0.5f*(a.y + b.y + c.y);
  o.z = 0.5f*(a.z + b.z + c.z); o.w = 0.5f*(a.w + b.w + c.w);
  *(float4*)(out + i) = o;
}

// ------ bf16 MFMA GEMM (TN), BK=64, XOR-swizzled LDS, 2-phase dbuf; bf16 output ------
__global__ __launch_bounds__(256) void gemm_tn(
    const unsigned short* __restrict__ A, const unsigned short* __restrict__ Bt,
    unsigned short* __restrict__ Cb, int M, int N, int K)
{
  __shared__ unsigned short As[2][128*64];
  __shared__ unsigned short Bs[2][128*64];
  int t = threadIdx.x;
  int wave = t >> 6, lane = t & 63;
  int brow = blockIdx.y*128, bcol = blockIdx.x*128;
  int wr = (wave >> 1)*64, wc = (wave & 1)*64;
  int fr = lane & 15, q = lane >> 4;
  int rin = lane >> 3, kslot = (lane & 7) ^ rin;

  f32x4 acc[4][4];
  #pragma unroll
  for (int a = 0; a < 4; a++)
    #pragma unroll
    for (int b = 0; b < 4; b++){ acc[a][b][0]=0.f; acc[a][b][1]=0.f; acc[a][b][2]=0.f; acc[a][b][3]=0.f; }

  int aoff[4][2], boff[4][2];
  #pragma unroll
  for (int mi = 0; mi < 4; mi++){
    int row = wr + mi*16 + fr;
    #pragma unroll
    for (int kk = 0; kk < 2; kk++) aoff[mi][kk] = row*64 + (((kk*4 + q) ^ (row & 7))*8);
  }
  #pragma unroll
  for (int ni = 0; ni < 4; ni++){
    int row = wc + ni*16 + fr;
    #pragma unroll
    for (int kk = 0; kk < 2; kk++) boff[ni][kk] = row*64 + (((kk*4 + q) ^ (row & 7))*8);
  }

  auto stage = [&](int buf, int k0){
    #pragma unroll
    for (int p = 0; p < 4; p++){
      int rsec = p*32 + wave*8;
      gl_lds(A  + (long)(brow + rsec + rin)*K + k0 + kslot*8, &As[buf][rsec*64]);
      gl_lds(Bt + (long)(bcol + rsec + rin)*K + k0 + kslot*8, &Bs[buf][rsec*64]);
    }
  };

  int nsteps = K >> 6;
  stage(0, 0);
  __syncthreads();
  int curb = 0;
  for (int s = 0; s < nsteps; s++){
    if (s + 1 < nsteps) stage(curb ^ 1, (s + 1)*64);
    const unsigned short* a_l = As[curb];
    const unsigned short* b_l = Bs[curb];
    #pragma unroll
    for (int kk = 0; kk < 2; kk++){
      bf16x8 af[4], bfv[4];
      #pragma unroll
      for (int mi = 0; mi < 4; mi++) af[mi]  = *(const bf16x8*)(a_l + aoff[mi][kk]);
      #pragma unroll
      for (int ni = 0; ni < 4; ni++) bfv[ni] = *(const bf16x8*)(b_l + boff[ni][kk]);
      #pragma unroll
      for (int mi = 0; mi < 4; mi++)
        #pragma unroll
        for (int ni = 0; ni < 4; ni++)
          acc[mi][ni] = __builtin_amdgcn_mfma_f32_16x16x32_bf16(af[mi], bfv[ni], acc[mi][ni], 0, 0, 0);
    }
    __syncthreads();
    curb ^= 1;
  }

  #pragma unroll
  for (int mi = 0; mi < 4; mi++){
    #pragma unroll
    for (int ni = 0; ni < 4; ni++){
      int col = bcol + wc + ni*16 + fr;
      #pragma unroll
      for (int r = 0; r < 4; r++){
        int row = brow + wr + mi*16 + q*4 + r;
        Cb[(long)row*N + col] = f2b(acc[mi][ni][r]);
      }
    }
  }
}

// ---------------- fused 3-layer GIP GEMM (both sides, z=2), dbuf ----------------
// epilogue: arg_l = c_l*S_l + b_l (one FMA) + v_exp_f32 (2^x) per layer
__global__ __launch_bounds__(512) void gip_gemm(
    const unsigned short* __restrict__ Y0, const unsigned short* __restrict__ Y1,
    const float* __restrict__ sim0, const float* __restrict__ sim1,
    const float* __restrict__ dva, const float* __restrict__ dvb,
    const float* __restrict__ sumps,
    const float* __restrict__ rs0, const float* __restrict__ rs1,
    unsigned short* __restrict__ o0, unsigned short* __restrict__ o1)
{
  __shared__ unsigned short As[2][128*64];
  __shared__ unsigned short Bs[2][128*64];
  const int K = 896;
  int side = blockIdx.z;
  const unsigned short* Y = side ? Y1 : Y0;
  const float* sim  = side ? sim1 : sim0;
  const float* dv   = side ? dvb : dva;
  const float* sums = sumps + side*3;
  const float* rs   = side ? rs1 : rs0;
  unsigned short* outp = side ? o1 : o0;
  int outoff = side ? N_DRUG : 0;

  int t = threadIdx.x;
  int wave = t >> 6, lane = t & 63;
  int brow = blockIdx.y*128, bcol = blockIdx.x*128;
  int wr = (wave >> 1)*32, wc = (wave & 1)*64;
  int fr = lane & 15, q = lane >> 4;
  int rin = lane >> 3, kslot = (lane & 7) ^ rin;

  f32x4 acc0[2][4], acc1[2][4], acc2[2][4];
  #pragma unroll
  for (int a = 0; a < 2; a++)
    #pragma unroll
    for (int b = 0; b < 4; b++){
      acc0[a][b][0]=0.f;acc0[a][b][1]=0.f;acc0[a][b][2]=0.f;acc0[a][b][3]=0.f;
      acc1[a][b][0]=0.f;acc1[a][b][1]=0.f;acc1[a][b][2]=0.f;acc1[a][b][3]=0.f;
      acc2[a][b][0]=0.f;acc2[a][b][1]=0.f;acc2[a][b][2]=0.f;acc2[a][b][3]=0.f;
    }

  int aoff[2][2], boff[4][2];
  #pragma unroll
  for (int mi = 0; mi < 2; mi++){
    int row = wr + mi*16 + fr;
    #pragma unroll
    for (int kk = 0; kk < 2; kk++) aoff[mi][kk] = row*64 + (((kk*4 + q) ^ (row & 7))*8);
  }
  #pragma unroll
  for (int ni = 0; ni < 4; ni++){
    int row = wc + ni*16 + fr;
    #pragma unroll
    for (int kk = 0; kk < 2; kk++) boff[ni][kk] = row*64 + (((kk*4 + q) ^ (row & 7))*8);
  }

  auto stage = [&](int buf, int k0){
    #pragma unroll
    for (int p = 0; p < 2; p++){
      int rsec = p*64 + wave*8;
      gl_lds(Y + (long)(brow + rsec + rin)*K + k0 + kslot*8, &As[buf][rsec*64]);
      gl_lds(Y + (long)(bcol + rsec + rin)*K + k0 + kslot*8, &Bs[buf][rsec*64]);
    }
  };

  int curb = 0, s = 0;
  stage(0, 0);
  __syncthreads();

#define GSTEP(ACC) { \
    if (s + 1 < 14) stage(curb ^ 1, (s + 1)*64); \
    const unsigned short* a_l = As[curb]; \
    const unsigned short* b_l = Bs[curb]; \
    _Pragma("unroll") \
    for (int kk = 0; kk < 2; kk++){ \
      bf16x8 af0 = *(const bf16x8*)(a_l + aoff[0][kk]); \
      bf16x8 af1 = *(const bf16x8*)(a_l + aoff[1][kk]); \
      _Pragma("unroll") \
      for (int ni = 0; ni < 4; ni++){ \
        bf16x8 bv = *(const bf16x8*)(b_l + boff[ni][kk]); \
        ACC[0][ni] = __builtin_amdgcn_mfma_f32_16x16x32_bf16(af0, bv, ACC[0][ni], 0, 0, 0); \
        ACC[1][ni] = __builtin_amdgcn_mfma_f32_16x16x32_bf16(af1, bv, ACC[1][ni], 0, 0, 0); \
      } \
    } \
    __syncthreads(); curb ^= 1; s++; }

  for (int i = 0; i < 8; i++) GSTEP(acc0)
  for (int i = 0; i < 4; i++) GSTEP(acc1)
  for (int i = 0; i < 2; i++) GSTEP(acc2)
#undef GSTEP

  // h_l = GAMMA*im_l*log2e ; arg_l = 2*h_l*S_l - h_l*(d_row + d_col)
  float h0 = GAMMA * ((float)N_DRUG / sums[0]) * LOG2E;
  float h1 = GAMMA * ((float)N_DRUG / sums[1]) * LOG2E;
  float h2 = GAMMA * ((float)N_DRUG / sums[2]) * LOG2E;
  float c0 = 2.f*h0, c1 = 2.f*h1, c2 = 2.f*h2;
  #pragma unroll
  for (int mi = 0; mi < 2; mi++){
    #pragma unroll
    for (int ni = 0; ni < 4; ni++){
      int col = bcol + wc + ni*16 + fr;
      float d0c = dv[col], d1c = dv[N_DRUG + col], d2c = dv[2*N_DRUG + col];
      float rc = rs[col];
      #pragma unroll
      for (int r = 0; r < 4; r++){
        int row = brow + wr + mi*16 + q*4 + r;
        float b0 = -h0*(dv[row] + d0c);
        float b1 = -h1*(dv[N_DRUG + row] + d1c);
        float b2 = -h2*(dv[2*N_DRUG + row] + d2c);
        float v = sim[(long)row*N_DRUG + col]
                + fexp2(fmaf(c0, acc0[mi][ni][r], b0))
                + fexp2(fmaf(c1, acc1[mi][ni][r], b1))
                + fexp2(fmaf(c2, acc2[mi][ni][r], b2));
        outp[(long)row*N_NODES + outoff + col] = f2b(v * rs[row] * rc);
      }
    }
  }
}

// ---------------- host ----------------
extern "C" void kernel_launch(void* const* d_in, const int* in_sizes, int n_in,
                              void* d_out, int out_size, void* d_ws, size_t ws_size,
                              hipStream_t stream){
  const float* x        = (const float*)d_in[0];
  const int*   ei       = (const int*)d_in[1];
  const float* adj      = (const float*)d_in[2];
  const float* drug_sim = (const float*)d_in[3];
  const float* dis_sim  = (const float*)d_in[4];
  const float* alpha1   = (const float*)d_in[5];
  const float* alpha2   = (const float*)d_in[6];
  const float* W[3]   = {(const float*)d_in[7],  (const float*)d_in[11], (const float*)d_in[15]};
  const float* as_[3] = {(const float*)d_in[8],  (const float*)d_in[12], (const float*)d_in[16]};
  const float* ad_[3] = {(const float*)d_in[9],  (const float*)d_in[13], (const float*)d_in[17]};
  const float* bs_[3] = {(const float*)d_in[10], (const float*)d_in[14], (const float*)d_in[18]};
  float* out = (float*)d_out;
  const int Fs[3] = {512, 256, 128};

  char* p = (char*)d_ws;
  auto alloc = [&](size_t bytes)->char*{
    char* r = p; p += (bytes + 255) & ~(size_t)255; return r;
  };
  unsigned short* xb  = (unsigned short*)alloc((size_t)N_NODES*N_NODES*2);
  // region wb..ycat0 is contiguous and fully dead by final-GEMM time -> hosts partial z=2
  unsigned short* wb  = (unsigned short*)alloc((size_t)N_NODES*512*2);
  unsigned short* XWb = (unsigned short*)alloc((size_t)N_NODES*512*2);
  unsigned short* HbL[3];
  HbL[0] = (unsigned short*)alloc((size_t)N_NODES*512*2);
  HbL[1] = (unsigned short*)alloc((size_t)N_NODES*256*2);
  HbL[2] = (unsigned short*)alloc((size_t)N_NODES*128*2);
  float* es    = (float*)alloc(N_NODES*4);
  float* edv   = (float*)alloc(N_NODES*4);
  float* exc   = (float*)alloc((size_t)E_TOT*4);
  int* cntcur  = (int*)alloc((size_t)2*N_NODES*4);
  int* cnt = cntcur, *cur = cntcur + N_NODES;
  int* cptr = (int*)alloc((N_NODES+1)*4);
  int* srcs  = (int*)alloc((size_t)E_TOT*4);
  int* dsts  = (int*)alloc((size_t)E_TOT*4);
  float* wcsr = (float*)alloc((size_t)E_TOT*4);
  unsigned short* ycat[2];
  ycat[0] = (unsigned short*)alloc((size_t)N_DRUG*896*2);
  ycat[1] = (unsigned short*)alloc((size_t)N_DRUG*896*2);
  float* dvv[2];
  dvv[0] = (float*)alloc((size_t)3*N_DRUG*4);
  dvv[1] = (float*)alloc((size_t)3*N_DRUG*4);
  float* sump = (float*)alloc(256);
  float* rsv[2];
  rsv[0] = (float*)alloc(N_DRUG*4);
  rsv[1] = (float*)alloc(N_DRUG*4);
  unsigned short* Abuf  = (unsigned short*)alloc((size_t)N_DRUG*N_NODES*2);
  unsigned short* Btbuf = (unsigned short*)alloc((size_t)N_DRUG*N_NODES*2);

  // split-K partials for layer-1 live in dead Abuf+Btbuf space
  float* pL1 = (float*)Abuf;
  // final-GEMM partials: z=0,1 in dead xb (exactly 2x 37.7MB); z=2 in dead wb..ycat0 span
  float* pF01 = (float*)xb;
  float* pF2  = (float*)wb;
  const long MN = (long)N_DRUG*N_DRUG;

  // --- prep: x cast, CSR build (+ one-time adj gather into CSR order) ---
  cast_bf16_k<<<4096, 256, 0, stream>>>(x, xb, (long)N_NODES*N_NODES);
  hipMemsetAsync(cntcur, 0, (size_t)2*N_NODES*4, stream);
  hist_k<<<(E_TOT+255)/256, 256, 0, stream>>>(ei, cnt);
  scan_k<<<1, 1024, 0, stream>>>(cnt, cptr);
  scatter_k<<<(E_TOT+255)/256, 256, 0, stream>>>(ei, adj, cptr, cur, srcs, dsts, wcsr);

  // --- 3 GAT layers ---
  const unsigned short* Ain = xb;
  int Kin = N_NODES;
  for (int l = 0; l < 3; l++){
    int F = Fs[l];
    tcast_k<<<dim3(F/32, Kin/32), dim3(32,8), 0, stream>>>(W[l], wb, Kin, F, Kin, 0);
    if (l == 0){
      gemm8p<<<dim3(F/256, N_NODES/256, 4), 512, 0, stream>>>(Ain, wb, pL1, pL1 + 2*(long)N_NODES*F, N_NODES, F, Kin, Kin/4);
      reduce4b_k<<<(int)(((long)N_NODES*F/4 + 255)/256), 256, 0, stream>>>(pL1, XWb, (long)N_NODES*F);
    } else {
      gemm_tn<<<dim3(F/128, N_NODES/128), 256, 0, stream>>>(Ain, wb, XWb, N_NODES, F, Kin);
    }
    dots_k<<<N_NODES, 64, 0, stream>>>(XWb, as_[l], ad_[l], es, edv, F);
    phase12_k<<<(E_TOT+255)/256, 256, 0, stream>>>(srcs, dsts, wcsr, es, edv, exc);
    if (F >= 256)
      agg4_k<<<N_NODES, F/4, 0, stream>>>(XWb, cptr, srcs, exc, bs_[l], HbL[l], F);
    else
      agg_k<<<N_NODES, 64, 0, stream>>>(XWb, cptr, srcs, exc, bs_[l], HbL[l], F);
    Ain = HbL[l]; Kin = F;
  }

  // --- GIP prep ---
  hipMemsetAsync(sump, 0, 24, stream);
  rownorm_all_k<<<dim3(N_DRUG, 6), 256, 0, stream>>>(HbL[0], HbL[1], HbL[2],
                                                     ycat[0], ycat[1], dvv[0], dvv[1]);
  vsum_diag_k<<<dim3(12, 8), 256, 0, stream>>>(dvv[0], dvv[1], sump,
                                               drug_sim, dis_sim, rsv[0], rsv[1]);

  // --- alpha transposes into concat buffers (merged z=2) ---
  // Abuf = [NK_drug | alpha2^T], Btbuf = [alpha1^T | NK_dis]
  tcast2_k<<<dim3(N_DRUG/32, N_DRUG/32, 2), dim3(32,8), 0, stream>>>(alpha2, alpha1, Abuf, Btbuf);

  // --- fused GIP -> normalized kernel (bf16), both sides in one launch ---
  gip_gemm<<<dim3(N_DRUG/128, N_DRUG/128, 2), 512, 0, stream>>>(
      ycat[0], ycat[1], drug_sim, dis_sim, dvv[0], dvv[1], sump, rsv[0], rsv[1], Abuf, Btbuf);

  // --- final: out = 0.5*(NK1@a1 + a2^T@NK2), K=6144, split-K x3 (kz=2048, nt=32) ---
  gemm8p<<<dim3(N_DRUG/256, N_DRUG/256, 3), 512, 0, stream>>>(Abuf, Btbuf, pF01, pF2, N_DRUG, N_DRUG, N_NODES, N_NODES/3);
  reduce3h_k<<<(int)((MN/4 + 255)/256), 256, 0, stream>>>(pF01, pF01 + MN, pF2, out, MN);

  (void)in_sizes; (void)n_in; (void)out_size; (void)ws_size;
}

// Round 15
// 557.616 us; speedup vs baseline: 1.1329x; 1.0078x over previous
//
#include <hip/hip_runtime.h>
#include <hip/hip_bf16.h>
#include <stdint.h>

#define N_NODES 6144
#define N_DRUG  3072
#define N_EDGE  196608
#define E_TOT   (N_EDGE + N_NODES)
#define GAMMA   0.03125f
#define LOG2E   1.44269504f

typedef __bf16 bf16x8 __attribute__((ext_vector_type(8)));
typedef float  f32x4  __attribute__((ext_vector_type(4)));

__device__ __forceinline__ unsigned short f2b(float f){
  union { float f; unsigned u; } v; v.f = f;
  unsigned r = v.u + 0x7FFFu + ((v.u >> 16) & 1u);
  return (unsigned short)(r >> 16);
}
__device__ __forceinline__ float b2f(unsigned short b){
  union { unsigned u; float f; } v; v.u = ((unsigned)b) << 16;
  return v.f;
}
__device__ __forceinline__ float fexp2(float x){
  float r; asm("v_exp_f32 %0, %1" : "=v"(r) : "v"(x)); return r;
}
__device__ __forceinline__ void gl_lds(const void* g, void* l){
  __builtin_amdgcn_global_load_lds((const __attribute__((address_space(1))) void*)g,
                                   (__attribute__((address_space(3))) void*)l, 16, 0, 0);
}

#define WAITVM(N) asm volatile("s_waitcnt vmcnt(" #N ")" ::: "memory")
#define SYNC() { __builtin_amdgcn_sched_barrier(0); __builtin_amdgcn_s_barrier(); __builtin_amdgcn_sched_barrier(0); }

// ---------------- elementwise / transpose casts ----------------
__global__ void cast_bf16_k(const float* __restrict__ in, unsigned short* __restrict__ out, long n){
  long i = ((long)blockIdx.x*blockDim.x + threadIdx.x)*4;
  long stride = (long)gridDim.x*blockDim.x*4;
  for (; i < n; i += stride){
    float4 v = *(const float4*)(in + i);
    ushort4 o;
    o.x = f2b(v.x); o.y = f2b(v.y); o.z = f2b(v.z); o.w = f2b(v.w);
    *(ushort4*)(out + i) = o;
  }
}

// out[c][OLD] at [c][OOFF + r] = bf16(in[r][c]); in is [R][Cd]
__global__ void tcast_k(const float* __restrict__ in, unsigned short* __restrict__ out,
                        int R, int Cd, int OLD, int OOFF){
  __shared__ float tile[32][33];
  int bx = blockIdx.x*32, by = blockIdx.y*32;
  int tx = threadIdx.x, ty = threadIdx.y;
  for (int i = ty; i < 32; i += 8) tile[i][tx] = in[(long)(by+i)*Cd + bx + tx];
  __syncthreads();
  for (int i = ty; i < 32; i += 8) out[(long)(bx+i)*OLD + OOFF + by + tx] = f2b(tile[tx][i]);
}

// z=0: alpha2 -> o0 at OOFF=N_DRUG ; z=1: alpha1 -> o1 at OOFF=0  (both 3072^2, OLD=N_NODES)
__global__ void tcast2_k(const float* __restrict__ a2, const float* __restrict__ a1,
                         unsigned short* __restrict__ o0, unsigned short* __restrict__ o1){
  __shared__ float tile[32][33];
  const float* in = blockIdx.z ? a1 : a2;
  unsigned short* out = blockIdx.z ? o1 : o0;
  int OOFF = blockIdx.z ? 0 : N_DRUG;
  int bx = blockIdx.x*32, by = blockIdx.y*32;
  int tx = threadIdx.x, ty = threadIdx.y;
  for (int i = ty; i < 32; i += 8) tile[i][tx] = in[(long)(by+i)*N_DRUG + bx + tx];
  __syncthreads();
  for (int i = ty; i < 32; i += 8) out[(long)(bx+i)*N_NODES + OOFF + by + tx] = f2b(tile[tx][i]);
}

// ---------------- CSR build ----------------
__global__ void hist_k(const int* __restrict__ ei, int* __restrict__ cnt){
  int i = blockIdx.x*blockDim.x + threadIdx.x;
  if (i >= E_TOT) return;
  int d = (i < N_EDGE) ? ei[N_EDGE + i] : (i - N_EDGE);
  atomicAdd(&cnt[d], 1);
}

__global__ void scan_k(const int* __restrict__ cnt, int* __restrict__ ptr){
  __shared__ int sums[1024];
  int t = threadIdx.x;
  int v[6]; int s = 0;
  #pragma unroll
  for (int i = 0; i < 6; i++){ v[i] = s; s += cnt[t*6 + i]; }
  sums[t] = s; __syncthreads();
  for (int off = 1; off < 1024; off <<= 1){
    int add = (t >= off) ? sums[t - off] : 0;
    __syncthreads();
    sums[t] += add;
    __syncthreads();
  }
  int base = (t == 0) ? 0 : sums[t-1];
  #pragma unroll
  for (int i = 0; i < 6; i++) ptr[t*6 + i] = base + v[i];
  if (t == 1023) ptr[N_NODES] = sums[1023];
}

// one-time: CSR scatter + adj gather into CSR order (layer-invariant edge weights)
__global__ void scatter_k(const int* __restrict__ ei, const float* __restrict__ adj,
                          const int* __restrict__ ptr, int* __restrict__ cur,
                          int* __restrict__ srcs, float* __restrict__ wcsr){
  int i = blockIdx.x*blockDim.x + threadIdx.x;
  if (i >= E_TOT) return;
  int s = (i < N_EDGE) ? ei[i] : (i - N_EDGE);
  int d = (i < N_EDGE) ? ei[N_EDGE + i] : (i - N_EDGE);
  int pos = ptr[d] + atomicAdd(&cur[d], 1);
  srcs[pos] = s;
  wcsr[pos] = (i < N_EDGE) ? adj[(long)s*N_NODES + d] : 1.0f;
}

// ---------------- GAT pieces ----------------
// reads bf16 XWb via ushort4
__global__ void dots_k(const unsigned short* __restrict__ XWb, const float* __restrict__ av,
                       const float* __restrict__ dv, float* __restrict__ es,
                       float* __restrict__ ed, int F){
  int n = blockIdx.x, l = threadIdx.x;
  float s = 0.f, d = 0.f;
  for (int f = l*4; f < F; f += 256){
    ushort4 u = *(const ushort4*)(XWb + (long)n*F + f);
    float4 a = *(const float4*)(av + f);
    float4 dd = *(const float4*)(dv + f);
    s += b2f(u.x)*a.x + b2f(u.y)*a.y + b2f(u.z)*a.z + b2f(u.w)*a.w;
    d += b2f(u.x)*dd.x + b2f(u.y)*dd.y + b2f(u.z)*dd.z + b2f(u.w)*dd.w;
  }
  #pragma unroll
  for (int off = 32; off > 0; off >>= 1){ s += __shfl_down(s, off); d += __shfl_down(d, off); }
  if (l == 0){ es[n] = s; ed[n] = d; }
}

// one block per node; blockDim = F/4; ushort4 gathers; attention weights computed
// inline (exc fusion): w = exp2(leaky(es[s]+ed[n])*log2e)*wcsr[j]; denom in-register
__global__ void agg4_k(const unsigned short* __restrict__ XWb, const int* __restrict__ ptr,
                       const int* __restrict__ srcs, const float* __restrict__ wcsr,
                       const float* __restrict__ es, const float* __restrict__ ed,
                       const float* __restrict__ bias,
                       unsigned short* __restrict__ Hb, int F){
  int n = blockIdx.x, t = threadIdx.x;
  int st = ptr[n], en = ptr[n+1];
  float edn = ed[n];
  float a0v = 0.f, a1v = 0.f, a2v = 0.f, a3v = 0.f, dsum = 0.f;
  int j = st;
  for (; j + 1 < en; j += 2){
    int s0 = srcs[j], s1 = srcs[j+1];
    float e0 = es[s0] + edn; e0 = (e0 > 0.f) ? e0 : 0.2f*e0;
    float e1 = es[s1] + edn; e1 = (e1 > 0.f) ? e1 : 0.2f*e1;
    float w0 = fexp2(e0*LOG2E) * wcsr[j];
    float w1 = fexp2(e1*LOG2E) * wcsr[j+1];
    ushort4 u0 = *(const ushort4*)(XWb + (long)s0*F + t*4);
    ushort4 u1 = *(const ushort4*)(XWb + (long)s1*F + t*4);
    dsum += w0 + w1;
    a0v += w0*b2f(u0.x) + w1*b2f(u1.x); a1v += w0*b2f(u0.y) + w1*b2f(u1.y);
    a2v += w0*b2f(u0.z) + w1*b2f(u1.z); a3v += w0*b2f(u0.w) + w1*b2f(u1.w);
  }
  if (j < en){
    int s0 = srcs[j];
    float e0 = es[s0] + edn; e0 = (e0 > 0.f) ? e0 : 0.2f*e0;
    float w0 = fexp2(e0*LOG2E) * wcsr[j];
    ushort4 u0 = *(const ushort4*)(XWb + (long)s0*F + t*4);
    dsum += w0;
    a0v += w0*b2f(u0.x); a1v += w0*b2f(u0.y); a2v += w0*b2f(u0.z); a3v += w0*b2f(u0.w);
  }
  float invd = 1.f/(dsum + 1e-16f);
  float4 b = *(const float4*)(bias + t*4);
  ushort4 ob;
  ob.x = f2b(fmaxf(a0v*invd + b.x, 0.f)); ob.y = f2b(fmaxf(a1v*invd + b.y, 0.f));
  ob.z = f2b(fmaxf(a2v*invd + b.z, 0.f)); ob.w = f2b(fmaxf(a3v*invd + b.w, 0.f));
  *(ushort4*)(Hb + (long)n*F + t*4) = ob;
}

// F = 128 variant: blockDim = 64, ushort2 per thread
__global__ void agg_k(const unsigned short* __restrict__ XWb, const int* __restrict__ ptr,
                      const int* __restrict__ srcs, const float* __restrict__ wcsr,
                      const float* __restrict__ es, const float* __restrict__ ed,
                      const float* __restrict__ bias,
                      unsigned short* __restrict__ Hb, int F){
  int n = blockIdx.x, t = threadIdx.x;
  int st = ptr[n], en = ptr[n+1];
  float edn = ed[n];
  float ax = 0.f, ay = 0.f, dsum = 0.f;
  int j = st;
  for (; j + 1 < en; j += 2){
    int s0 = srcs[j], s1 = srcs[j+1];
    float e0 = es[s0] + edn; e0 = (e0 > 0.f) ? e0 : 0.2f*e0;
    float e1 = es[s1] + edn; e1 = (e1 > 0.f) ? e1 : 0.2f*e1;
    float a0 = fexp2(e0*LOG2E) * wcsr[j];
    float a1 = fexp2(e1*LOG2E) * wcsr[j+1];
    ushort2 u0 = *(const ushort2*)(XWb + (long)s0*F + t*2);
    ushort2 u1 = *(const ushort2*)(XWb + (long)s1*F + t*2);
    dsum += a0 + a1;
    ax += a0*b2f(u0.x) + a1*b2f(u1.x);
    ay += a0*b2f(u0.y) + a1*b2f(u1.y);
  }
  if (j < en){
    int s0 = srcs[j];
    float e0 = es[s0] + edn; e0 = (e0 > 0.f) ? e0 : 0.2f*e0;
    float a = fexp2(e0*LOG2E) * wcsr[j];
    ushort2 u = *(const ushort2*)(XWb + (long)s0*F + t*2);
    dsum += a;
    ax += a*b2f(u.x); ay += a*b2f(u.y);
  }
  float invd = 1.f/(dsum + 1e-16f);
  float2 b = *(const float2*)(bias + t*2);
  ushort2 o;
  o.x = f2b(fmaxf(ax*invd + b.x, 0.f));
  o.y = f2b(fmaxf(ay*invd + b.y, 0.f));
  *(ushort2*)(Hb + (long)n*F + t*2) = o;
}

// ---------------- GIP prep (merged over 6 segments: seg = side*3 + layer) ------
__global__ void rownorm_all_k(const unsigned short* __restrict__ H0, const unsigned short* __restrict__ H1,
                              const unsigned short* __restrict__ H2,
                              unsigned short* __restrict__ y0, unsigned short* __restrict__ y1,
                              float* __restrict__ dv0, float* __restrict__ dv1){
  int seg = blockIdx.y;
  int side = seg / 3, layer = seg % 3;
  int F = 512 >> layer;
  const unsigned short* H = (layer == 0) ? H0 : (layer == 1) ? H1 : H2;
  H += (size_t)(side ? N_DRUG : 0) * F;
  unsigned short* yb = ((side ? y1 : y0) + ((layer == 0) ? 0 : (layer == 1) ? 512 : 768));
  float* dvec = (side ? dv1 : dv0) + layer*N_DRUG;

  int r = blockIdx.x, t = threadIdx.x;
  __shared__ float ra[256], rb[256];
  float mn = 3.4e38f, mx = -3.4e38f;
  for (int f = t; f < F; f += 256){
    float v = b2f(H[(long)r*F + f]);
    mn = fminf(mn, v); mx = fmaxf(mx, v);
  }
  ra[t] = mn; rb[t] = mx; __syncthreads();
  for (int s2 = 128; s2 > 0; s2 >>= 1){
    if (t < s2){ ra[t] = fminf(ra[t], ra[t+s2]); rb[t] = fmaxf(rb[t], rb[t+s2]); }
    __syncthreads();
  }
  mn = ra[0]; mx = rb[0];
  __syncthreads();
  float sc = 1.f/(mx - mn + 1e-12f);
  float s = 0.f;
  for (int f = t; f < F; f += 256){
    float v = (b2f(H[(long)r*F + f]) - mn)*sc;
    unsigned short b = f2b(v);
    yb[(long)r*896 + f] = b;
    float vb = b2f(b);
    s += vb*vb;
  }
  ra[t] = s; __syncthreads();
  for (int s2 = 128; s2 > 0; s2 >>= 1){
    if (t < s2) ra[t] += ra[t+s2];
    __syncthreads();
  }
  if (t == 0) dvec[r] = ra[0];
}

// y<6: single block (x==0) sums dvec segment -> sump[y] (no atomics, no memset)
// y=6,7: diag rsqrt per side (12 x-blocks)
__global__ void vsum_diag_k(const float* __restrict__ dv0, const float* __restrict__ dv1,
                            float* __restrict__ sump,
                            const float* __restrict__ sim0, const float* __restrict__ sim1,
                            float* __restrict__ rs0, float* __restrict__ rs1){
  int y = blockIdx.y;
  int t = threadIdx.x;
  if (y < 6){
    if (blockIdx.x != 0) return;
    int side = y / 3, layer = y % 3;
    const float* v = (side ? dv1 : dv0) + layer*N_DRUG;
    __shared__ float red[256];
    float s = 0.f;
    for (int i = t; i < N_DRUG; i += 256) s += v[i];
    red[t] = s; __syncthreads();
    for (int s2 = 128; s2 > 0; s2 >>= 1){ if (t < s2) red[t] += red[t+s2]; __syncthreads(); }
    if (t == 0) sump[y] = red[0];
  } else {
    int side = y - 6;
    int i = blockIdx.x*256 + t;
    const float* sim = side ? sim1 : sim0;
    float* rs = side ? rs1 : rs0;
    if (i < N_DRUG) rs[i] = rsqrtf(sim[(long)i*N_DRUG + i] + 3.0f);
  }
}

// ====================== 256x256 8-phase GEMM (TN), 2 K-tiles/iter ======================
// Partial P[z]: z<2 -> P + z*M*N ; z>=2 -> Palt + (z-2)*M*N. kz/64 MUST be even.
__global__ __launch_bounds__(512, 2) void gemm8p(
    const unsigned short* __restrict__ A, const unsigned short* __restrict__ Bt,
    float* __restrict__ P, float* __restrict__ Palt, int M, int N, int K, int kz)
{
  __shared__ unsigned short lds[2][2][16384];   // [buf][A/B][256*64]
  int t = threadIdx.x;
  int lane = t & 63, wave = t >> 6;
  int wm = wave >> 2, wn = wave & 3;

  // XCD-aware bijective swizzle (grid x*y % 8 == 0 at our launches)
  int nbx = gridDim.x;
  int nwg = nbx * gridDim.y;
  int bid = blockIdx.y * nbx + blockIdx.x;
  int cpx = nwg >> 3;
  int swz = (bid & 7) * cpx + (bid >> 3);
  long brow = (long)(swz / nbx) * 256;
  long bcol = (long)(swz % nbx) * 256;
  long k0 = (long)blockIdx.z * kz;
  int nt = kz >> 6;                             // even by construction

  // staging: one gl_lds line = 512thr x 16B = 8KB = 64 rows x 128B
  int sr = wave*8 + (lane >> 3);                // row 0..63 within line
  int cg = (lane & 7) ^ (lane >> 3);            // pre-swizzled source chunk
  const unsigned short* gA = A  + (brow + sr)*(long)K + k0 + cg*8;
  const unsigned short* gB = Bt + (bcol + sr)*(long)K + k0 + cg*8;
  unsigned ldsw = wave * 512;                   // wave-uniform dest (elems)

  auto stage = [&](int b, int mat, int h, int tk){
    const unsigned short* g = (mat ? gB : gA) + (long)(h*128)*K + (long)tk*64;
    unsigned short* d = &lds[b][mat][h*8192 + ldsw];
    gl_lds(g, d);
    gl_lds(g + (long)64*K, d + 4096);
  };

  // reader: row R, chunk c -> elem R*64 + ((c ^ (R&7))*8)
  int fr = lane & 15, q = lane >> 4;
  int lo = fr*64 + ((q ^ (fr & 7))*8);
  int dk = (lo ^ 32) - lo;                      // chunk +4 (kk=1) slot flip

  f32x4 acc[8][4];
  #pragma unroll
  for (int a = 0; a < 8; a++)
    #pragma unroll
    for (int b = 0; b < 4; b++){ acc[a][b][0]=0.f; acc[a][b][1]=0.f; acc[a][b][2]=0.f; acc[a][b][3]=0.f; }
  bf16x8 af[4][2], bf[4][2];

  const unsigned short* a0p = &lds[0][0][wm*8192 + lo];
  const unsigned short* b0p = &lds[0][1][wn*4096 + lo];
  const unsigned short* a1p = &lds[1][0][wm*8192 + lo];
  const unsigned short* b1p = &lds[1][1][wn*4096 + lo];

#define RD_AF_LO(ab) { _Pragma("unroll") for (int j = 0; j < 4; ++j){ \
    af[j][0] = *(const bf16x8*)((ab) + j*1024); af[j][1] = *(const bf16x8*)((ab) + j*1024 + dk); } }
#define RD_AF_HI(ab) { _Pragma("unroll") for (int j = 0; j < 4; ++j){ \
    af[j][0] = *(const bf16x8*)((ab) + (4+j)*1024); af[j][1] = *(const bf16x8*)((ab) + (4+j)*1024 + dk); } }
#define RD_BF_LO(bb) { _Pragma("unroll") for (int j = 0; j < 2; ++j){ \
    bf[j][0] = *(const bf16x8*)((bb) + j*1024); bf[j][1] = *(const bf16x8*)((bb) + j*1024 + dk); } }
#define RD_BF_HI(bb) { _Pragma("unroll") for (int j = 2; j < 4; ++j){ \
    bf[j][0] = *(const bf16x8*)((bb) + j*1024); bf[j][1] = *(const bf16x8*)((bb) + j*1024 + dk); } }
#define MFMA_Q(MB, NB) { __builtin_amdgcn_s_setprio(1); \
    _Pragma("unroll") for (int kk = 0; kk < 2; ++kk) \
      _Pragma("unroll") for (int mi = 0; mi < 4; ++mi) \
        _Pragma("unroll") for (int ni = (NB); ni < (NB)+2; ++ni) \
          acc[(MB)+mi][ni] = __builtin_amdgcn_mfma_f32_16x16x32_bf16(af[mi][kk], bf[ni][kk], acc[(MB)+mi][ni], 0, 0, 0); \
    __builtin_amdgcn_s_setprio(0); }

  // prologue: tile0 fully -> buf0; tile1 B-halves -> buf1 (12 loads, drain to 4)
  stage(0,0,0,0); stage(0,0,1,0); stage(0,1,0,0); stage(0,1,1,0);
  stage(1,1,0,1); stage(1,1,1,1);
  WAITVM(4);
  SYNC();

  int half = nt >> 1;
  for (int i = 0; i < half; ++i){
    int t1 = 2*i+1, t2 = 2*i+2, t3 = 2*i+3;
    bool s2 = t2 < nt, s3 = t3 < nt;
    // ===== tile 2i from buf0 =====
    RD_AF_LO(a0p); RD_BF_LO(b0p);
    stage(1,0,0,t1);
    SYNC(); MFMA_Q(0,0); SYNC();
    RD_BF_HI(b0p);
    stage(1,0,1,t1);
    SYNC(); MFMA_Q(0,2); SYNC();
    RD_AF_HI(a0p);
    if (s2) stage(0,1,0,t2);
    SYNC(); MFMA_Q(4,0); SYNC();
    if (s2){ stage(0,1,1,t2); WAITVM(4); } else { WAITVM(0); }
    SYNC(); MFMA_Q(4,2); SYNC();
    // ===== tile 2i+1 from buf1 =====
    RD_AF_LO(a1p); RD_BF_LO(b1p);
    if (s2) stage(0,0,0,t2);
    SYNC(); MFMA_Q(0,0); SYNC();
    RD_BF_HI(b1p);
    if (s2) stage(0,0,1,t2);
    SYNC(); MFMA_Q(0,2); SYNC();
    RD_AF_HI(a1p);
    if (s3) stage(1,1,0,t3);
    SYNC(); MFMA_Q(4,0); SYNC();
    if (s3){ stage(1,1,1,t3); WAITVM(4); } else { WAITVM(0); }
    SYNC(); MFMA_Q(4,2); SYNC();
  }
#undef RD_AF_LO
#undef RD_AF_HI
#undef RD_BF_LO
#undef RD_BF_HI
#undef MFMA_Q

  int z = blockIdx.z;
  float* Pz = (z < 2) ? (P + (long)z*M*N) : (Palt + (long)(z-2)*M*N);
  #pragma unroll
  for (int mi = 0; mi < 8; ++mi){
    #pragma unroll
    for (int ni = 0; ni < 4; ++ni){
      long col = bcol + wn*64 + ni*16 + fr;
      #pragma unroll
      for (int r = 0; r < 4; ++r){
        long row = brow + wm*128 + mi*16 + q*4 + r;
        Pz[row*N + col] = acc[mi][ni][r];
      }
    }
  }
}

// XWb = bf16(p0+p1+p2+p3)
__global__ void reduce4b_k(const float* __restrict__ p, unsigned short* __restrict__ outb, long n){
  long i = ((long)blockIdx.x*blockDim.x + threadIdx.x)*4;
  if (i >= n) return;
  float4 s = *(const float4*)(p + i);
  #pragma unroll
  for (int z = 1; z < 4; z++){
    float4 x = *(const float4*)(p + (long)z*n + i);
    s.x += x.x; s.y += x.y; s.z += x.z; s.w += x.w;
  }
  ushort4 o; o.x = f2b(s.x); o.y = f2b(s.y); o.z = f2b(s.z); o.w = f2b(s.w);
  *(ushort4*)(outb + i) = o;
}

// out = 0.5*(pa+pb+pc)
__global__ void reduce3h_k(const float* __restrict__ pa, const float* __restrict__ pb,
                           const float* __restrict__ pc, float* __restrict__ out, long n){
  long i = ((long)blockIdx.x*blockDim.x + threadIdx.x)*4;
  if (i >= n) return;
  float4 a = *(const float4*)(pa + i);
  float4 b = *(const float4*)(pb + i);
  float4 c = *(const float4*)(pc + i);
  float4 o;
  o.x = 0.5f*(a.x + b.x + c.x); o.y = 0.5f*(a.y + b.y + c.y);
  o.z = 0.5f*(a.z + b.z + c.z); o.w = 0.5f*(a.w + b.w + c.w);
  *(float4*)(out + i) = o;
}

// ------ bf16 MFMA GEMM (TN), BK=64, XOR-swizzled LDS, 2-phase dbuf; bf16 output ------
__global__ __launch_bounds__(256) void gemm_tn(
    const unsigned short* __restrict__ A, const unsigned short* __restrict__ Bt,
    unsigned short* __restrict__ Cb, int M, int N, int K)
{
  __shared__ unsigned short As[2][128*64];
  __shared__ unsigned short Bs[2][128*64];
  int t = threadIdx.x;
  int wave = t >> 6, lane = t & 63;
  int brow = blockIdx.y*128, bcol = blockIdx.x*128;
  int wr = (wave >> 1)*64, wc = (wave & 1)*64;
  int fr = lane & 15, q = lane >> 4;
  int rin = lane >> 3, kslot = (lane & 7) ^ rin;

  f32x4 acc[4][4];
  #pragma unroll
  for (int a = 0; a < 4; a++)
    #pragma unroll
    for (int b = 0; b < 4; b++){ acc[a][b][0]=0.f; acc[a][b][1]=0.f; acc[a][b][2]=0.f; acc[a][b][3]=0.f; }

  int aoff[4][2], boff[4][2];
  #pragma unroll
  for (int mi = 0; mi < 4; mi++){
    int row = wr + mi*16 + fr;
    #pragma unroll
    for (int kk = 0; kk < 2; kk++) aoff[mi][kk] = row*64 + (((kk*4 + q) ^ (row & 7))*8);
  }
  #pragma unroll
  for (int ni = 0; ni < 4; ni++){
    int row = wc + ni*16 + fr;
    #pragma unroll
    for (int kk = 0; kk < 2; kk++) boff[ni][kk] = row*64 + (((kk*4 + q) ^ (row & 7))*8);
  }

  auto stage = [&](int buf, int k0){
    #pragma unroll
    for (int p = 0; p < 4; p++){
      int rsec = p*32 + wave*8;
      gl_lds(A  + (long)(brow + rsec + rin)*K + k0 + kslot*8, &As[buf][rsec*64]);
      gl_lds(Bt + (long)(bcol + rsec + rin)*K + k0 + kslot*8, &Bs[buf][rsec*64]);
    }
  };

  int nsteps = K >> 6;
  stage(0, 0);
  __syncthreads();
  int curb = 0;
  for (int s = 0; s < nsteps; s++){
    if (s + 1 < nsteps) stage(curb ^ 1, (s + 1)*64);
    const unsigned short* a_l = As[curb];
    const unsigned short* b_l = Bs[curb];
    #pragma unroll
    for (int kk = 0; kk < 2; kk++){
      bf16x8 af[4], bfv[4];
      #pragma unroll
      for (int mi = 0; mi < 4; mi++) af[mi]  = *(const bf16x8*)(a_l + aoff[mi][kk]);
      #pragma unroll
      for (int ni = 0; ni < 4; ni++) bfv[ni] = *(const bf16x8*)(b_l + boff[ni][kk]);
      #pragma unroll
      for (int mi = 0; mi < 4; mi++)
        #pragma unroll
        for (int ni = 0; ni < 4; ni++)
          acc[mi][ni] = __builtin_amdgcn_mfma_f32_16x16x32_bf16(af[mi], bfv[ni], acc[mi][ni], 0, 0, 0);
    }
    __syncthreads();
    curb ^= 1;
  }

  #pragma unroll
  for (int mi = 0; mi < 4; mi++){
    #pragma unroll
    for (int ni = 0; ni < 4; ni++){
      int col = bcol + wc + ni*16 + fr;
      #pragma unroll
      for (int r = 0; r < 4; r++){
        int row = brow + wr + mi*16 + q*4 + r;
        Cb[(long)row*N + col] = f2b(acc[mi][ni][r]);
      }
    }
  }
}

// ---------------- fused 3-layer GIP GEMM (both sides, z=2), dbuf ----------------
// epilogue: arg_l = c_l*S_l + b_l (one FMA) + v_exp_f32 (2^x) per layer
__global__ __launch_bounds__(512) void gip_gemm(
    const unsigned short* __restrict__ Y0, const unsigned short* __restrict__ Y1,
    const float* __restrict__ sim0, const float* __restrict__ sim1,
    const float* __restrict__ dva, const float* __restrict__ dvb,
    const float* __restrict__ sumps,
    const float* __restrict__ rs0, const float* __restrict__ rs1,
    unsigned short* __restrict__ o0, unsigned short* __restrict__ o1)
{
  __shared__ unsigned short As[2][128*64];
  __shared__ unsigned short Bs[2][128*64];
  const int K = 896;
  int side = blockIdx.z;
  const unsigned short* Y = side ? Y1 : Y0;
  const float* sim  = side ? sim1 : sim0;
  const float* dv   = side ? dvb : dva;
  const float* sums = sumps + side*3;
  const float* rs   = side ? rs1 : rs0;
  unsigned short* outp = side ? o1 : o0;
  int outoff = side ? N_DRUG : 0;

  int t = threadIdx.x;
  int wave = t >> 6, lane = t & 63;
  int brow = blockIdx.y*128, bcol = blockIdx.x*128;
  int wr = (wave >> 1)*32, wc = (wave & 1)*64;
  int fr = lane & 15, q = lane >> 4;
  int rin = lane >> 3, kslot = (lane & 7) ^ rin;

  f32x4 acc0[2][4], acc1[2][4], acc2[2][4];
  #pragma unroll
  for (int a = 0; a < 2; a++)
    #pragma unroll
    for (int b = 0; b < 4; b++){
      acc0[a][b][0]=0.f;acc0[a][b][1]=0.f;acc0[a][b][2]=0.f;acc0[a][b][3]=0.f;
      acc1[a][b][0]=0.f;acc1[a][b][1]=0.f;acc1[a][b][2]=0.f;acc1[a][b][3]=0.f;
      acc2[a][b][0]=0.f;acc2[a][b][1]=0.f;acc2[a][b][2]=0.f;acc2[a][b][3]=0.f;
    }

  int aoff[2][2], boff[4][2];
  #pragma unroll
  for (int mi = 0; mi < 2; mi++){
    int row = wr + mi*16 + fr;
    #pragma unroll
    for (int kk = 0; kk < 2; kk++) aoff[mi][kk] = row*64 + (((kk*4 + q) ^ (row & 7))*8);
  }
  #pragma unroll
  for (int ni = 0; ni < 4; ni++){
    int row = wc + ni*16 + fr;
    #pragma unroll
    for (int kk = 0; kk < 2; kk++) boff[ni][kk] = row*64 + (((kk*4 + q) ^ (row & 7))*8);
  }

  auto stage = [&](int buf, int k0){
    #pragma unroll
    for (int p = 0; p < 2; p++){
      int rsec = p*64 + wave*8;
      gl_lds(Y + (long)(brow + rsec + rin)*K + k0 + kslot*8, &As[buf][rsec*64]);
      gl_lds(Y + (long)(bcol + rsec + rin)*K + k0 + kslot*8, &Bs[buf][rsec*64]);
    }
  };

  int curb = 0, s = 0;
  stage(0, 0);
  __syncthreads();

#define GSTEP(ACC) { \
    if (s + 1 < 14) stage(curb ^ 1, (s + 1)*64); \
    const unsigned short* a_l = As[curb]; \
    const unsigned short* b_l = Bs[curb]; \
    _Pragma("unroll") \
    for (int kk = 0; kk < 2; kk++){ \
      bf16x8 af0 = *(const bf16x8*)(a_l + aoff[0][kk]); \
      bf16x8 af1 = *(const bf16x8*)(a_l + aoff[1][kk]); \
      _Pragma("unroll") \
      for (int ni = 0; ni < 4; ni++){ \
        bf16x8 bv = *(const bf16x8*)(b_l + boff[ni][kk]); \
        ACC[0][ni] = __builtin_amdgcn_mfma_f32_16x16x32_bf16(af0, bv, ACC[0][ni], 0, 0, 0); \
        ACC[1][ni] = __builtin_amdgcn_mfma_f32_16x16x32_bf16(af1, bv, ACC[1][ni], 0, 0, 0); \
      } \
    } \
    __syncthreads(); curb ^= 1; s++; }

  for (int i = 0; i < 8; i++) GSTEP(acc0)
  for (int i = 0; i < 4; i++) GSTEP(acc1)
  for (int i = 0; i < 2; i++) GSTEP(acc2)
#undef GSTEP

  // h_l = GAMMA*im_l*log2e ; arg_l = 2*h_l*S_l - h_l*(d_row + d_col)
  float h0 = GAMMA * ((float)N_DRUG / sums[0]) * LOG2E;
  float h1 = GAMMA * ((float)N_DRUG / sums[1]) * LOG2E;
  float h2 = GAMMA * ((float)N_DRUG / sums[2]) * LOG2E;
  float c0 = 2.f*h0, c1 = 2.f*h1, c2 = 2.f*h2;
  #pragma unroll
  for (int mi = 0; mi < 2; mi++){
    #pragma unroll
    for (int ni = 0; ni < 4; ni++){
      int col = bcol + wc + ni*16 + fr;
      float d0c = dv[col], d1c = dv[N_DRUG + col], d2c = dv[2*N_DRUG + col];
      float rc = rs[col];
      #pragma unroll
      for (int r = 0; r < 4; r++){
        int row = brow + wr + mi*16 + q*4 + r;
        float b0 = -h0*(dv[row] + d0c);
        float b1 = -h1*(dv[N_DRUG + row] + d1c);
        float b2 = -h2*(dv[2*N_DRUG + row] + d2c);
        float v = sim[(long)row*N_DRUG + col]
                + fexp2(fmaf(c0, acc0[mi][ni][r], b0))
                + fexp2(fmaf(c1, acc1[mi][ni][r], b1))
                + fexp2(fmaf(c2, acc2[mi][ni][r], b2));
        outp[(long)row*N_NODES + outoff + col] = f2b(v * rs[row] * rc);
      }
    }
  }
}

// ---------------- host ----------------
extern "C" void kernel_launch(void* const* d_in, const int* in_sizes, int n_in,
                              void* d_out, int out_size, void* d_ws, size_t ws_size,
                              hipStream_t stream){
  const float* x        = (const float*)d_in[0];
  const int*   ei       = (const int*)d_in[1];
  const float* adj      = (const float*)d_in[2];
  const float* drug_sim = (const float*)d_in[3];
  const float* dis_sim  = (const float*)d_in[4];
  const float* alpha1   = (const float*)d_in[5];
  const float* alpha2   = (const float*)d_in[6];
  const float* W[3]   = {(const float*)d_in[7],  (const float*)d_in[11], (const float*)d_in[15]};
  const float* as_[3] = {(const float*)d_in[8],  (const float*)d_in[12], (const float*)d_in[16]};
  const float* ad_[3] = {(const float*)d_in[9],  (const float*)d_in[13], (const float*)d_in[17]};
  const float* bs_[3] = {(const float*)d_in[10], (const float*)d_in[14], (const float*)d_in[18]};
  float* out = (float*)d_out;
  const int Fs[3] = {512, 256, 128};

  char* p = (char*)d_ws;
  auto alloc = [&](size_t bytes)->char*{
    char* r = p; p += (bytes + 255) & ~(size_t)255; return r;
  };
  unsigned short* xb  = (unsigned short*)alloc((size_t)N_NODES*N_NODES*2);
  unsigned short* wb  = (unsigned short*)alloc((size_t)N_NODES*512*2);
  unsigned short* XWb = (unsigned short*)alloc((size_t)N_NODES*512*2);
  unsigned short* HbL[3];
  HbL[0] = (unsigned short*)alloc((size_t)N_NODES*512*2);
  HbL[1] = (unsigned short*)alloc((size_t)N_NODES*256*2);
  HbL[2] = (unsigned short*)alloc((size_t)N_NODES*128*2);
  float* es    = (float*)alloc(N_NODES*4);
  float* edv   = (float*)alloc(N_NODES*4);
  int* cntcur  = (int*)alloc((size_t)2*N_NODES*4);
  int* cnt = cntcur, *cur = cntcur + N_NODES;
  int* cptr = (int*)alloc((N_NODES+1)*4);
  int* srcs  = (int*)alloc((size_t)E_TOT*4);
  float* wcsr = (float*)alloc((size_t)E_TOT*4);
  unsigned short* ycat[2];
  ycat[0] = (unsigned short*)alloc((size_t)N_DRUG*896*2);
  ycat[1] = (unsigned short*)alloc((size_t)N_DRUG*896*2);
  float* dvv[2];
  dvv[0] = (float*)alloc((size_t)3*N_DRUG*4);
  dvv[1] = (float*)alloc((size_t)3*N_DRUG*4);
  float* sump = (float*)alloc(256);
  float* rsv[2];
  rsv[0] = (float*)alloc(N_DRUG*4);
  rsv[1] = (float*)alloc(N_DRUG*4);
  unsigned short* Abuf  = (unsigned short*)alloc((size_t)N_DRUG*N_NODES*2);
  unsigned short* Btbuf = (unsigned short*)alloc((size_t)N_DRUG*N_NODES*2);
  // dedicated z=2 partial for the final GEMM (no liveness gymnastics)
  float* pF2 = (float*)alloc((size_t)N_DRUG*N_DRUG*4);

  // split-K partials for layer-1 live in dead Abuf space (50.3MB <= 75.5MB)
  float* pL1 = (float*)Abuf;
  // final-GEMM partials z=0,1 in dead xb (exactly 2x 37.7MB)
  float* pF01 = (float*)xb;
  const long MN = (long)N_DRUG*N_DRUG;

  // --- prep: x cast, CSR build (+ one-time adj gather into CSR order) ---
  cast_bf16_k<<<4096, 256, 0, stream>>>(x, xb, (long)N_NODES*N_NODES);
  hipMemsetAsync(cntcur, 0, (size_t)2*N_NODES*4, stream);
  hist_k<<<(E_TOT+255)/256, 256, 0, stream>>>(ei, cnt);
  scan_k<<<1, 1024, 0, stream>>>(cnt, cptr);
  scatter_k<<<(E_TOT+255)/256, 256, 0, stream>>>(ei, adj, cptr, cur, srcs, wcsr);

  // --- 3 GAT layers ---
  const unsigned short* Ain = xb;
  int Kin = N_NODES;
  for (int l = 0; l < 3; l++){
    int F = Fs[l];
    tcast_k<<<dim3(F/32, Kin/32), dim3(32,8), 0, stream>>>(W[l], wb, Kin, F, Kin, 0);
    if (l == 0){
      gemm8p<<<dim3(F/256, N_NODES/256, 4), 512, 0, stream>>>(Ain, wb, pL1, pL1 + 2*(long)N_NODES*F, N_NODES, F, Kin, Kin/4);
      reduce4b_k<<<(int)(((long)N_NODES*F/4 + 255)/256), 256, 0, stream>>>(pL1, XWb, (long)N_NODES*F);
    } else {
      gemm_tn<<<dim3(F/128, N_NODES/128), 256, 0, stream>>>(Ain, wb, XWb, N_NODES, F, Kin);
    }
    dots_k<<<N_NODES, 64, 0, stream>>>(XWb, as_[l], ad_[l], es, edv, F);
    if (F >= 256)
      agg4_k<<<N_NODES, F/4, 0, stream>>>(XWb, cptr, srcs, wcsr, es, edv, bs_[l], HbL[l], F);
    else
      agg_k<<<N_NODES, 64, 0, stream>>>(XWb, cptr, srcs, wcsr, es, edv, bs_[l], HbL[l], F);
    Ain = HbL[l]; Kin = F;
  }

  // --- GIP prep ---
  rownorm_all_k<<<dim3(N_DRUG, 6), 256, 0, stream>>>(HbL[0], HbL[1], HbL[2],
                                                     ycat[0], ycat[1], dvv[0], dvv[1]);
  vsum_diag_k<<<dim3(12, 8), 256, 0, stream>>>(dvv[0], dvv[1], sump,
                                               drug_sim, dis_sim, rsv[0], rsv[1]);

  // --- alpha transposes into concat buffers (merged z=2) ---
  // Abuf = [NK_drug | alpha2^T], Btbuf = [alpha1^T | NK_dis]
  tcast2_k<<<dim3(N_DRUG/32, N_DRUG/32, 2), dim3(32,8), 0, stream>>>(alpha2, alpha1, Abuf, Btbuf);

  // --- fused GIP -> normalized kernel (bf16), both sides in one launch ---
  gip_gemm<<<dim3(N_DRUG/128, N_DRUG/128, 2), 512, 0, stream>>>(
      ycat[0], ycat[1], drug_sim, dis_sim, dvv[0], dvv[1], sump, rsv[0], rsv[1], Abuf, Btbuf);

  // --- final: out = 0.5*(NK1@a1 + a2^T@NK2), K=6144, split-K x3 (kz=2048, nt=32) ---
  gemm8p<<<dim3(N_DRUG/256, N_DRUG/256, 3), 512, 0, stream>>>(Abuf, Btbuf, pF01, pF2, N_DRUG, N_DRUG, N_NODES, N_NODES/3);
  reduce3h_k<<<(int)((MN/4 + 255)/256), 256, 0, stream>>>(pF01, pF01 + MN, pF2, out, MN);

  (void)in_sizes; (void)n_in; (void)out_size; (void)ws_size;
}